// Round 6
// baseline (715.247 us; speedup 1.0000x reference)
//
#include <hip/hip_runtime.h>
#include <math.h>

// FNO2d: B=8, H=W=128, WIDTH=32, MODES=12, NL=6
// Spectral conv via partial DFT with register-rotator twiddles.
// Head: fc1+fc3 fused in one MFMA kernel (bf16 hi/lo x3); fc4+fc5 fp32.

#define NL 6

typedef unsigned short u16;
typedef __attribute__((ext_vector_type(8))) short short8v;
typedef __attribute__((ext_vector_type(8))) unsigned short ushort8v;
typedef __attribute__((ext_vector_type(4))) unsigned short ushort4v;
typedef __attribute__((ext_vector_type(4))) float f32x4;

__device__ __forceinline__ float gelu_f(float x){
  return 0.5f*x*(1.0f + erff(x*0.70710678118654752f));
}
__device__ __forceinline__ u16 f2bf(float x){
  unsigned u = __float_as_uint(x);
  u += 0x7FFF + ((u>>16)&1);
  return (u16)(u>>16);
}
__device__ __forceinline__ float bf2f(u16 h){
  return __uint_as_float(((unsigned)h)<<16);
}

// ---------------- fc0: x[B,H,W,4] @ [4,32] + b -> y[B,32,H,W] ----------------
__global__ __launch_bounds__(256) void k_fc0(const float* __restrict__ x,
                      const float* __restrict__ W, const float* __restrict__ b,
                      float* __restrict__ y){
  __shared__ float Ws[128];
  __shared__ float bs[32];
  int t = threadIdx.x;
  if (t < 128) Ws[t] = W[t];
  if (t < 32)  bs[t] = b[t];
  __syncthreads();
  int pix = blockIdx.x*256 + t;
  float4 xv = *reinterpret_cast<const float4*>(x + (size_t)pix*4);
  int bb = pix >> 14, hw = pix & 16383;
  float* yp = y + (size_t)bb*32*16384 + hw;
  #pragma unroll
  for (int c=0;c<32;c++){
    float acc = bs[c] + xv.x*Ws[c] + xv.y*Ws[32+c] + xv.z*Ws[64+c] + xv.w*Ws[96+c];
    yp[(size_t)c*16384] = acc;
  }
}

// ------- one-time weight transpose: spec_w[l][hf][i][o][kym][kx][ri] ------
// -> wT[l][hf][kym][kx][i][o][ri]
__global__ __launch_bounds__(256) void k_wtrans(const float* __restrict__ w, float* __restrict__ wT){
  __shared__ float buf[16][32][25];
  int t=threadIdx.x;
  int beta = blockIdx.x;            // 6*2*12*2 = 288
  int l = beta/48, r = beta%48;
  int hf = r/24; int r2 = r%24;
  int kym = r2>>1; int i0 = (r2&1)*16;
  const float* src = w + (size_t)l*589824 + (size_t)hf*294912 + kym*24;
  float* dst = wT + (size_t)l*589824 + (size_t)hf*294912 + (size_t)kym*24576;
  for (int j=t; j<12288; j+=256){
    int i = j/768, rem = j%768, o = rem/24, kxri = rem%24;
    buf[i][o][kxri] = src[(size_t)(i0+i)*9216 + o*288 + kxri];
  }
  __syncthreads();
  for (int j=t; j<12288; j+=256){
    int kx = j>>10, rem = j&1023, i = rem>>6, orr = rem&63, o = orr>>1, ri = orr&1;
    dst[(size_t)kx*2048 + (i0+i)*64 + o*2 + ri] = buf[i][o][kx*2+ri];
  }
}

// ------- head weight prep: W1[32,256]->W1T[n][32] h/l; W3[256,128]->W3T[n][256] h/l
__global__ __launch_bounds__(256) void k_wprep(const float* __restrict__ W1, const float* __restrict__ W3,
                       u16* __restrict__ W1h, u16* __restrict__ W1l,
                       u16* __restrict__ W3h, u16* __restrict__ W3l){
  __shared__ float buf[32][132];
  int t = threadIdx.x, bid = blockIdx.x;   // 9 blocks
  if (bid < 8){
    int k0 = bid*32;
    for (int i=t;i<4096;i+=256){ int k=i>>7, n=i&127; buf[k][n] = W3[(size_t)(k0+k)*128 + n]; }
    __syncthreads();
    int n = t>>1, kq = t&1;
    #pragma unroll
    for (int kk=0;kk<16;kk++){
      int k = kq*16 + kk;
      float v = buf[k][n];
      u16 hh = f2bf(v);
      W3h[(size_t)n*256 + k0 + k] = hh;
      W3l[(size_t)n*256 + k0 + k] = f2bf(v - bf2f(hh));
    }
  } else {
    int n = t;
    #pragma unroll
    for (int c=0;c<32;c++){
      float v = W1[(size_t)c*256 + n];
      u16 hh = f2bf(v);
      W1h[n*32 + c] = hh;
      W1l[n*32 + c] = f2bf(v - bf2f(hh));
    }
  }
}

// ---------- fused 2D forward DFT: y[b][c][h][w] -> F2[bc][kyi][kxri] --------
// 512 threads. Phase A: thread (h, wq) rotator-shared over its 32-w quarter,
// reading y straight from global (lane l covers floats [32l,32l+32) per wave).
// Phase B: 288 threads, one (kyi,kx) each, full-h rotator (re-init per 32).
__global__ __launch_bounds__(512) void k_dft2d(const float* __restrict__ y, float* __restrict__ F2){
  __shared__ float T1[128][28];
  int t = threadIdx.x;
  int bc = blockIdx.x;           // 256
  {
    int h = t>>2, wq = t&3;
    const float* row = y + (size_t)bc*16384 + h*128 + wq*32;
    float cr[12], ci[12], stc[12], sts[12], aR[12], aI[12];
    #pragma unroll
    for (int k=0;k<12;k++){
      aR[k]=0.f; aI[k]=0.f;
      float s,c;
      sincospif((float)(k*wq*32)*(1.0f/64.0f), &s, &c);
      cr[k]=c; ci[k]=s;
      sincospif(k*(1.0f/64.0f), &s, &c); stc[k]=c; sts[k]=s;
    }
    #pragma unroll
    for (int q=0;q<8;q++){
      float4 xq = *reinterpret_cast<const float4*>(row + q*4);
      float xa[4]={xq.x,xq.y,xq.z,xq.w};
      #pragma unroll
      for (int e=0;e<4;e++){
        float xw = xa[e];
        #pragma unroll
        for (int k=0;k<12;k++){
          aR[k] += xw*cr[k];
          aI[k] -= xw*ci[k];
          float nc = cr[k]*stc[k] - ci[k]*sts[k];
          ci[k]    = cr[k]*sts[k] + ci[k]*stc[k];
          cr[k] = nc;
        }
      }
    }
    #pragma unroll
    for (int k=0;k<12;k++){
      aR[k] += __shfl_xor(aR[k],1); aR[k] += __shfl_xor(aR[k],2);
      aI[k] += __shfl_xor(aI[k],1); aI[k] += __shfl_xor(aI[k],2);
    }
    if (wq==0){
      #pragma unroll
      for (int q=0;q<6;q++){
        float4 v; v.x=aR[2*q]; v.y=aI[2*q]; v.z=aR[2*q+1]; v.w=aI[2*q+1];
        *reinterpret_cast<float4*>(&T1[h][4*q]) = v;
      }
    }
  }
  __syncthreads();
  if (t < 288){
    int kx = t%12, kyi = t/12;
    int ky = (kyi<12)? kyi : kyi+104;
    float aR=0.f, aI=0.f;
    float sc, ss; sincospif((float)ky*(1.0f/64.0f), &ss, &sc);
    #pragma unroll
    for (int hq=0; hq<4; hq++){
      float c0,s0; sincospif((float)(ky*hq*32)*(1.0f/64.0f), &s0, &c0);
      #pragma unroll 8
      for (int hh=0; hh<32; hh++){
        int h = hq*32+hh;
        float2 a = *reinterpret_cast<const float2*>(&T1[h][2*kx]);
        aR += a.x*c0 + a.y*s0;
        aI += a.y*c0 - a.x*s0;
        float nc = c0*sc - s0*ss; s0 = c0*ss + s0*sc; c0 = nc;
      }
    }
    F2[(size_t)bc*576 + kyi*24 + 2*kx]   = aR;
    F2[(size_t)bc*576 + kyi*24 + 2*kx+1] = aI;
  }
}

// ---------------- mode mix with transposed weights --------------------------
// F2[bc][kyi][kxri] x wT -> G3[b][col(2kx+ri)][o][kyi]   (kyi contiguous!)
__global__ __launch_bounds__(256) void k_mix(const float* __restrict__ F2, const float* __restrict__ wTl,
                     float* __restrict__ G3){
  __shared__ float fr[12][33], fi[12][33];
  int t=threadIdx.x;
  int kyi = blockIdx.x>>3, b = blockIdx.x&7;   // 192 blocks
  for (int j=t; j<768; j+=256){
    int c = j/24, col = j%24;
    float v = F2[((size_t)(b*32+c)*24 + kyi)*24 + col];
    if (col&1) fi[col>>1][c] = v; else fr[col>>1][c] = v;
  }
  __syncthreads();
  int hf = kyi<12?0:1, kym = kyi<12?kyi:kyi-12;
  const float* wb = wTl + (size_t)(hf*12+kym)*24576;
  for (int j=t; j<384; j+=256){
    int o = j&31, kx = j>>5;
    const float* wp = wb + kx*2048 + o*2;
    float gr=0.f, gi=0.f;
    #pragma unroll 8
    for (int i=0;i<32;i++){
      float2 wv = *reinterpret_cast<const float2*>(&wp[i*64]);
      float ar = fr[kx][i], ai = fi[kx][i];
      gr += ar*wv.x - ai*wv.y;
      gi += ar*wv.y + ai*wv.x;
    }
    G3[(((size_t)b*24 + 2*kx  )*32 + o)*24 + kyi] = gr;
    G3[(((size_t)b*24 + 2*kx+1)*32 + o)*24 + kyi] = gi;
  }
}

// --------- combine: fused inverse-H DFT (vectorized G3 reads) + inverse-W DFT
//           + conv1x1 + bias terms + GELU. LAST=1 emits bf16 hi/lo [pix][32].
template<int LAST>
__global__ __launch_bounds__(256) void k_combine(const float* __restrict__ yin, const float* __restrict__ G3,
                         const float* __restrict__ x,
                         const float* __restrict__ wWl, const float* __restrict__ wbl,
                         const float* __restrict__ bWl, const float* __restrict__ bbl,
                         const float* __restrict__ cWl, const float* __restrict__ cbl,
                         float* __restrict__ yout,
                         u16* __restrict__ yh, u16* __restrict__ yl){
  __shared__ float ysT[128][33];
  __shared__ float s1[32][25];
  __shared__ float cw[24], sw[24];
  int t=threadIdx.x;
  int b = blockIdx.x>>7, h = blockIdx.x&127;
  if (t<24){ int ky = t<12? t : t+104;
    float s,c; sincospif((float)(ky*h)*(1.0f/64.0f), &s, &c); cw[t]=c; sw[t]=s; }
  for (int i=t;i<4096;i+=256){ int c=i>>7, w=i&127;
    ysT[w][c] = yin[(((size_t)(b*32+c))*128+h)*128+w]; }
  __syncthreads();
  // inverse-H DFT: s1[o][col] from G3, kyi-contiguous float4 loads
  for (int j=t; j<768; j+=256){
    int o = j&31, col = j>>5;
    int kx2 = col & ~1;
    const float* gpr = G3 + (((size_t)b*24 + kx2)*32 + o)*24;
    const float* gpi = gpr + 768;   // col kx2+1
    float ar[24], ai[24];
    #pragma unroll
    for (int q=0;q<6;q++){
      *reinterpret_cast<float4*>(&ar[4*q]) = *reinterpret_cast<const float4*>(gpr + 4*q);
      *reinterpret_cast<float4*>(&ai[4*q]) = *reinterpret_cast<const float4*>(gpi + 4*q);
    }
    float acc=0.f;
    if (!(col&1)){
      #pragma unroll
      for (int kyi=0;kyi<24;kyi++) acc += ar[kyi]*cw[kyi] - ai[kyi]*sw[kyi];
    } else {
      #pragma unroll
      for (int kyi=0;kyi<24;kyi++) acc += ar[kyi]*sw[kyi] + ai[kyi]*cw[kyi];
    }
    s1[o][col] = acc*(1.0f/16384.0f);
  }
  __syncthreads();
  int w = t&127;
  int og = __builtin_amdgcn_readfirstlane(t>>7);   // wave-uniform 0/1
  float xv[32];
  #pragma unroll
  for (int c=0;c<32;c++) xv[c] = ysT[w][c];
  float ct[12], st[12];
  ct[0]=1.f; st[0]=0.f;
  float c1,s1v; sincospif(w*(1.0f/64.0f), &s1v, &c1);
  #pragma unroll
  for (int k=0;k<11;k++){ ct[k+1] = ct[k]*c1 - st[k]*s1v; st[k+1] = ct[k]*s1v + st[k]*c1; }
  float gx = h*(1.0f/127.0f), gy = w*(1.0f/127.0f);
  float4 xm = *reinterpret_cast<const float4*>(x + (((size_t)(b*128+h))*128+w)*4);
  float m1=xm.y, m2=xm.z, m3=xm.w;
  const float* wo  = wWl + og*512;                 // [16][32]
  float accv[16];
  #pragma unroll
  for (int oi=0;oi<16;oi++){
    int o = og*16+oi;
    float bse = wbl[o] + bbl[o] + cbl[o] + gx*bWl[o*2] + gy*bWl[o*2+1]
              + m1*cWl[o*3] + m2*cWl[o*3+1] + m3*cWl[o*3+2];
    float spec = s1[o][0];
    #pragma unroll
    for (int kx=1;kx<12;kx++) spec += 2.0f*(s1[o][2*kx]*ct[kx] - s1[o][2*kx+1]*st[kx]);
    accv[oi] = bse + spec;
  }
  #pragma unroll
  for (int c=0;c<32;c++){
    float xc = xv[c];
    #pragma unroll
    for (int oi=0;oi<16;oi++) accv[oi] += wo[oi*32+c]*xc;
  }
  if constexpr (!LAST){
    #pragma unroll
    for (int oi=0;oi<16;oi++){
      int o = og*16+oi;
      yout[(((size_t)(b*32+o))*128+h)*128+w] = gelu_f(accv[oi]);
    }
  } else {
    __syncthreads();     // all ysT reads done (xv in regs); reuse ysT as [w][o]
    #pragma unroll
    for (int oi=0;oi<16;oi++) ysT[w][og*16+oi] = gelu_f(accv[oi]);
    __syncthreads();
    int wr = t>>1, hf2 = t&1;
    size_t pix = (size_t)b*16384 + h*128 + wr;
    ushort8v h8a, l8a, h8b, l8b;
    #pragma unroll
    for (int q=0;q<8;q++){
      float v = ysT[wr][hf2*16 + q];
      u16 hh = f2bf(v);
      h8a[q] = hh; l8a[q] = f2bf(v - bf2f(hh));
      float v2 = ysT[wr][hf2*16 + 8 + q];
      u16 hh2 = f2bf(v2);
      h8b[q] = hh2; l8b[q] = f2bf(v2 - bf2f(hh2));
    }
    *reinterpret_cast<ushort8v*>(yh + pix*32 + hf2*16)     = h8a;
    *reinterpret_cast<ushort8v*>(yh + pix*32 + hf2*16 + 8) = h8b;
    *reinterpret_cast<ushort8v*>(yl + pix*32 + hf2*16)     = l8a;
    *reinterpret_cast<ushort8v*>(yl + pix*32 + hf2*16 + 8) = l8b;
  }
}

// ------- fused head fc1+fc3 via MFMA bf16x3 -> A2[n3][p] fp32, GELU --------
__global__ __launch_bounds__(256,3) void k_headm(
    const u16* __restrict__ Yh, const u16* __restrict__ Yl,     // [pix][32]
    const u16* __restrict__ W1h, const u16* __restrict__ W1l,   // [256][32]
    const float* __restrict__ b1,
    const u16* __restrict__ W3h, const u16* __restrict__ W3l,   // [128][256]
    const float* __restrict__ b3,
    float* __restrict__ A2){
  __shared__ u16 Ach[128][40], Acl[128][40];
  __shared__ u16 W3ch[128][40], W3cl[128][40];
  __shared__ float b1s[256];
  __shared__ float b3s[128];
  int t = threadIdx.x;
  int wv = t>>6, lane = t&63, lr = lane&15, lg = lane>>4;
  int P0 = blockIdx.x*128;
  b1s[t] = b1[t];
  if (t<128) b3s[t] = b3[t];
  int wn3 = wv>>1, wp = wv&1;
  int p0w = wv*32;
  // Y fragments: kt-invariant, straight from global (wave reads 16 rows x 64B)
  short8v ybh[2], ybl[2];
  #pragma unroll
  for (int j=0;j<2;j++){
    size_t p = (size_t)P0 + p0w + j*16 + lr;
    ybh[j] = *reinterpret_cast<const short8v*>(Yh + p*32 + lg*8);
    ybl[j] = *reinterpret_cast<const short8v*>(Yl + p*32 + lg*8);
  }
  f32x4 acc3[4][4];
  #pragma unroll
  for (int i=0;i<4;i++)
    #pragma unroll
    for (int j=0;j<4;j++) acc3[i][j] = (f32x4){0.f,0.f,0.f,0.f};
  __syncthreads();   // b1s/b3s visible

  for (int kt=0; kt<8; ++kt){
    // ---- issue W3 chunk loads (written to LDS below) ----
    int srow = t>>1, soff = (t&1)*16;
    const u16* g3h = W3h + (size_t)srow*256 + kt*32 + soff;
    const u16* g3l = W3l + (size_t)srow*256 + kt*32 + soff;
    ushort8v wh0 = *reinterpret_cast<const ushort8v*>(g3h);
    ushort8v wh1 = *reinterpret_cast<const ushort8v*>(g3h+8);
    ushort8v wl0 = *reinterpret_cast<const ushort8v*>(g3l);
    ushort8v wl1 = *reinterpret_cast<const ushort8v*>(g3l+8);
    // ---- fc1: A1 chunk [128p][32n1] ----
    f32x4 a1[2][2];
    #pragma unroll
    for (int i=0;i<2;i++)
      #pragma unroll
      for (int j=0;j<2;j++) a1[i][j] = (f32x4){0.f,0.f,0.f,0.f};
    #pragma unroll
    for (int i=0;i<2;i++){
      int n1 = kt*32 + i*16 + lr;
      short8v w1f = *reinterpret_cast<const short8v*>(W1h + (size_t)n1*32 + lg*8);
      short8v w1g = *reinterpret_cast<const short8v*>(W1l + (size_t)n1*32 + lg*8);
      #pragma unroll
      for (int j=0;j<2;j++){
        a1[i][j] = __builtin_amdgcn_mfma_f32_16x16x32_bf16(w1f, ybh[j], a1[i][j], 0,0,0);
        a1[i][j] = __builtin_amdgcn_mfma_f32_16x16x32_bf16(w1f, ybl[j], a1[i][j], 0,0,0);
        a1[i][j] = __builtin_amdgcn_mfma_f32_16x16x32_bf16(w1g, ybh[j], a1[i][j], 0,0,0);
      }
    }
    // gelu + split -> Ac chunk LDS ([p][n1loc]); D rows=n1(4lg+reg), cols=p(lr)
    #pragma unroll
    for (int i=0;i<2;i++){
      int n1b = kt*32 + i*16 + 4*lg;
      #pragma unroll
      for (int j=0;j<2;j++){
        int p = p0w + j*16 + lr;
        ushort4v hv, lv;
        #pragma unroll
        for (int r=0;r<4;r++){
          float v = gelu_f(a1[i][j][r] + b1s[n1b+r]);
          u16 hh = f2bf(v);
          hv[r] = hh; lv[r] = f2bf(v - bf2f(hh));
        }
        *reinterpret_cast<ushort4v*>(&Ach[p][i*16+4*lg]) = hv;
        *reinterpret_cast<ushort4v*>(&Acl[p][i*16+4*lg]) = lv;
      }
    }
    // ---- write W3 chunk ----
    *reinterpret_cast<ushort8v*>(&W3ch[srow][soff])   = wh0;
    *reinterpret_cast<ushort8v*>(&W3ch[srow][soff+8]) = wh1;
    *reinterpret_cast<ushort8v*>(&W3cl[srow][soff])   = wl0;
    *reinterpret_cast<ushort8v*>(&W3cl[srow][soff+8]) = wl1;
    __syncthreads();
    // ---- fc3 accumulate ----
    short8v abh[4], abl[4];
    #pragma unroll
    for (int j=0;j<4;j++){
      int pb = wp*64 + j*16 + lr;
      abh[j] = *reinterpret_cast<const short8v*>(&Ach[pb][lg*8]);
      abl[j] = *reinterpret_cast<const short8v*>(&Acl[pb][lg*8]);
    }
    #pragma unroll
    for (int i=0;i<4;i++){
      int n3 = wn3*64 + i*16 + lr;
      short8v w3f = *reinterpret_cast<const short8v*>(&W3ch[n3][lg*8]);
      short8v w3g = *reinterpret_cast<const short8v*>(&W3cl[n3][lg*8]);
      #pragma unroll
      for (int j=0;j<4;j++){
        acc3[i][j] = __builtin_amdgcn_mfma_f32_16x16x32_bf16(w3f, abh[j], acc3[i][j], 0,0,0);
        acc3[i][j] = __builtin_amdgcn_mfma_f32_16x16x32_bf16(w3f, abl[j], acc3[i][j], 0,0,0);
        acc3[i][j] = __builtin_amdgcn_mfma_f32_16x16x32_bf16(w3g, abh[j], acc3[i][j], 0,0,0);
      }
    }
    __syncthreads();
  }
  // epilogue: D rows=n3 (4lg+reg), cols=p (lr); A2[n3][131072p]
  #pragma unroll
  for (int i=0;i<4;i++){
    int n3b = wn3*64 + i*16 + 4*lg;
    #pragma unroll
    for (int j=0;j<4;j++){
      int p = P0 + wp*64 + j*16 + lr;
      #pragma unroll
      for (int r=0;r<4;r++){
        A2[(size_t)(n3b+r)*131072 + p] = gelu_f(acc3[i][j][r] + b3s[n3b+r]);
      }
    }
  }
}

// ------ fused fc4+fc5: A2[k][p] @ W4[128,128]+b4, dot w5, +b5 -> out[p] -----
__global__ __launch_bounds__(256) void k_last(const float* __restrict__ A, const float* __restrict__ W4,
                   const float* __restrict__ b4, const float* __restrict__ w5,
                   const float* __restrict__ b5, float* __restrict__ out){
  __shared__ __align__(16) float As[32][132];
  __shared__ __align__(16) float Bs[32][132];
  __shared__ float b4s[128], w5s[128];
  __shared__ float part[4][128];
  int t=threadIdx.x;
  if (t<128){ b4s[t]=b4[t]; w5s[t]=w5[t]; }
  size_t p0 = (size_t)blockIdx.x*128;
  int tx=t&15, ty=t>>4;
  float acc[8][8]={};
  for (int kc=0;kc<128;kc+=32){
    for (int i=t;i<1024;i+=256){ int k=i>>5, f=i&31;
      *reinterpret_cast<float4*>(&As[k][f*4]) =
        *reinterpret_cast<const float4*>(&A[(size_t)(kc+k)*131072 + p0 + f*4]); }
    for (int i=t;i<1024;i+=256){ int k=i>>5, f=i&31;
      *reinterpret_cast<float4*>(&Bs[k][f*4]) =
        *reinterpret_cast<const float4*>(&W4[(size_t)(kc+k)*128 + f*4]); }
    __syncthreads();
    #pragma unroll 8
    for (int k=0;k<32;k++){
      float a[8], bb[8];
      *reinterpret_cast<float4*>(a)    = *reinterpret_cast<const float4*>(&As[k][tx*4]);
      *reinterpret_cast<float4*>(a+4)  = *reinterpret_cast<const float4*>(&As[k][64+tx*4]);
      *reinterpret_cast<float4*>(bb)   = *reinterpret_cast<const float4*>(&Bs[k][ty*4]);
      *reinterpret_cast<float4*>(bb+4) = *reinterpret_cast<const float4*>(&Bs[k][64+ty*4]);
      #pragma unroll
      for (int i=0;i<8;i++)
        #pragma unroll
        for (int j=0;j<8;j++) acc[i][j] += a[i]*bb[j];
    }
    __syncthreads();
  }
  float s[8];
  #pragma unroll
  for (int i=0;i<8;i++){
    float si = 0.f;
    #pragma unroll
    for (int j=0;j<8;j++){
      int n = (j<4)? ty*4+j : 64+ty*4+(j-4);
      si += (acc[i][j] + b4s[n]) * w5s[n];
    }
    si += __shfl_xor(si, 16);
    si += __shfl_xor(si, 32);
    s[i] = si;
  }
  int wv = t>>6;
  if ((t&63) < 16){
    #pragma unroll
    for (int i=0;i<8;i++){
      int m = (i<4)? tx*4+i : 64+tx*4+(i-4);
      part[wv][m] = s[i];
    }
  }
  __syncthreads();
  if (t<128){
    out[p0 + t] = part[0][t]+part[1][t]+part[2][t]+part[3][t] + b5[0];
  }
}

extern "C" void kernel_launch(void* const* d_in, const int* in_sizes, int n_in,
                              void* d_out, int out_size, void* d_ws, size_t ws_size,
                              hipStream_t stream){
  const float* x     = (const float*)d_in[0];
  const float* fc0_W = (const float*)d_in[1];
  const float* fc0_b = (const float*)d_in[2];
  const float* spec_w= (const float*)d_in[3];
  const float* wW    = (const float*)d_in[4];
  const float* wb    = (const float*)d_in[5];
  const float* bW    = (const float*)d_in[6];
  const float* bb    = (const float*)d_in[7];
  const float* cW    = (const float*)d_in[8];
  const float* cb    = (const float*)d_in[9];
  const float* fc1_W = (const float*)d_in[10];
  const float* fc1_b = (const float*)d_in[11];
  const float* fc3_W = (const float*)d_in[12];
  const float* fc3_b = (const float*)d_in[13];
  const float* fc4_W = (const float*)d_in[14];
  const float* fc4_b = (const float*)d_in[15];
  const float* fc5_W = (const float*)d_in[16];
  const float* fc5_b = (const float*)d_in[17];
  float* out = (float*)d_out;
  float* ws  = (float*)d_ws;

  float* y_a = ws;                         // 4,194,304
  float* y_b = y_a + 4194304;              // 4,194,304
  float* wT  = y_b + 4194304;              // 3,538,944
  float* F2  = wT + 3538944;               //   147,456
  float* G3  = F2 + 147456;                //   147,456  (end 12,222,464)
  // overlays (stream-ordered):
  u16*   Yhh = (u16*)y_a;                  // final-layer y hi  [pix][32]
  u16*   Yll_ = (u16*)y_a + 4194304;       // final-layer y lo
  float* A2  = y_b;                        // 16,777,216 floats (wT/F2/G3 dead)
  float* WP  = ws + 20971520;              // head weight prep region
  u16*   W1h = (u16*)WP;                   //  8,192 u16
  u16*   W1l = W1h + 8192;
  u16*   W3h = W1l + 8192;                 // 32,768 u16
  u16*   W3l = W3h + 32768;

  k_fc0<<<512,256,0,stream>>>(x, fc0_W, fc0_b, y_a);
  k_wtrans<<<288,256,0,stream>>>(spec_w, wT);
  k_wprep<<<9,256,0,stream>>>(fc1_W, fc3_W, W1h, W1l, W3h, W3l);

  for (int l=0;l<NL;l++){
    float* yin  = (l&1)? y_b : y_a;
    float* yout = (l&1)? y_a : y_b;
    k_dft2d<<<256,512,0,stream>>>(yin, F2);
    k_mix<<<192,256,0,stream>>>(F2, wT + (size_t)l*589824, G3);
    if (l < NL-1){
      k_combine<0><<<1024,256,0,stream>>>(yin, G3, x,
                                     wW + (size_t)l*1024, wb + (size_t)l*32,
                                     bW + (size_t)l*64,  bb + (size_t)l*32,
                                     cW + (size_t)l*96,  cb + (size_t)l*32,
                                     yout, nullptr, nullptr);
    } else {
      k_combine<1><<<1024,256,0,stream>>>(yin, G3, x,
                                     wW + (size_t)l*1024, wb + (size_t)l*32,
                                     bW + (size_t)l*64,  bb + (size_t)l*32,
                                     cW + (size_t)l*96,  cb + (size_t)l*32,
                                     nullptr, Yhh, Yll_);
    }
  }

  k_headm<<<1024,256,0,stream>>>(Yhh, Yll_, W1h, W1l, fc1_b, W3h, W3l, fc3_b, A2);
  k_last<<<1024,256,0,stream>>>(A2, fc4_W, fc4_b, fc5_W, fc5_b, out);
}

// Round 7
// 617.582 us; speedup vs baseline: 1.1581x; 1.1581x over previous
//
#include <hip/hip_runtime.h>
#include <math.h>

// FNO2d: B=8, H=W=128, WIDTH=32, MODES=12, NL=6
// Spectral conv via partial DFT (R4 structure). Head fully fused:
// fc1+fc3+fc4+fc5 in one MFMA kernel (bf16 hi/lo x3), out written directly.

#define NL 6

typedef unsigned short u16;
typedef __attribute__((ext_vector_type(8))) short short8v;
typedef __attribute__((ext_vector_type(8))) unsigned short ushort8v;
typedef __attribute__((ext_vector_type(4))) unsigned short ushort4v;
typedef __attribute__((ext_vector_type(4))) float f32x4;

// A&S 7.1.26 erf: max abs err 1.5e-7, branchless (vs libm erff ~2x cost)
__device__ __forceinline__ float gelu_f(float x){
  float z  = x*0.70710678118654752f;
  float az = fabsf(z);
  float t  = 1.0f/(1.0f + 0.3275911f*az);
  float p  = t*(0.254829592f + t*(-0.284496736f + t*(1.421413741f +
             t*(-1.453152027f + t*1.061405429f))));
  float e  = __expf(-z*z);
  float er = copysignf(1.0f - p*e, z);
  return 0.5f*x*(1.0f + er);
}
__device__ __forceinline__ u16 f2bf(float x){
  unsigned u = __float_as_uint(x);
  u += 0x7FFF + ((u>>16)&1);
  return (u16)(u>>16);
}
__device__ __forceinline__ float bf2f(u16 h){
  return __uint_as_float(((unsigned)h)<<16);
}

// ---------------- fc0: x[B,H,W,4] @ [4,32] + b -> y[B,32,H,W] ----------------
__global__ __launch_bounds__(256) void k_fc0(const float* __restrict__ x,
                      const float* __restrict__ W, const float* __restrict__ b,
                      float* __restrict__ y){
  __shared__ float Ws[128];
  __shared__ float bs[32];
  int t = threadIdx.x;
  if (t < 128) Ws[t] = W[t];
  if (t < 32)  bs[t] = b[t];
  __syncthreads();
  int pix = blockIdx.x*256 + t;
  float4 xv = *reinterpret_cast<const float4*>(x + (size_t)pix*4);
  int bb = pix >> 14, hw = pix & 16383;
  float* yp = y + (size_t)bb*32*16384 + hw;
  #pragma unroll
  for (int c=0;c<32;c++){
    float acc = bs[c] + xv.x*Ws[c] + xv.y*Ws[32+c] + xv.z*Ws[64+c] + xv.w*Ws[96+c];
    yp[(size_t)c*16384] = acc;
  }
}

// ------- one-time weight transpose: spec_w[l][hf][i][o][kym][kx][ri] ------
// -> wT[l][hf][kym][kx][i][o][ri]
__global__ __launch_bounds__(256) void k_wtrans(const float* __restrict__ w, float* __restrict__ wT){
  __shared__ float buf[16][32][25];
  int t=threadIdx.x;
  int beta = blockIdx.x;            // 6*2*12*2 = 288
  int l = beta/48, r = beta%48;
  int hf = r/24; int r2 = r%24;
  int kym = r2>>1; int i0 = (r2&1)*16;
  const float* src = w + (size_t)l*589824 + (size_t)hf*294912 + kym*24;
  float* dst = wT + (size_t)l*589824 + (size_t)hf*294912 + (size_t)kym*24576;
  for (int j=t; j<12288; j+=256){
    int i = j/768, rem = j%768, o = rem/24, kxri = rem%24;
    buf[i][o][kxri] = src[(size_t)(i0+i)*9216 + o*288 + kxri];
  }
  __syncthreads();
  for (int j=t; j<12288; j+=256){
    int kx = j>>10, rem = j&1023, i = rem>>6, orr = rem&63, o = orr>>1, ri = orr&1;
    dst[(size_t)kx*2048 + (i0+i)*64 + o*2 + ri] = buf[i][o][kx*2+ri];
  }
}

// ------- head weight prep: W1->[n1][32] h/l; W3->[n3][256] h/l; W4->[n4][128] h/l
__global__ __launch_bounds__(256) void k_wprep(const float* __restrict__ W1, const float* __restrict__ W3,
                       const float* __restrict__ W4,
                       u16* __restrict__ W1h, u16* __restrict__ W1l,
                       u16* __restrict__ W3h, u16* __restrict__ W3l,
                       u16* __restrict__ W4h, u16* __restrict__ W4l){
  __shared__ float buf[32][132];
  int t = threadIdx.x, bid = blockIdx.x;   // 13 blocks
  if (bid < 8){
    int k0 = bid*32;
    for (int i=t;i<4096;i+=256){ int k=i>>7, n=i&127; buf[k][n] = W3[(size_t)(k0+k)*128 + n]; }
    __syncthreads();
    int n = t>>1, kq = t&1;
    #pragma unroll
    for (int kk=0;kk<16;kk++){
      int k = kq*16 + kk;
      float v = buf[k][n];
      u16 hh = f2bf(v);
      W3h[(size_t)n*256 + k0 + k] = hh;
      W3l[(size_t)n*256 + k0 + k] = f2bf(v - bf2f(hh));
    }
  } else if (bid == 8){
    int n = t;
    #pragma unroll
    for (int c=0;c<32;c++){
      float v = W1[(size_t)c*256 + n];
      u16 hh = f2bf(v);
      W1h[n*32 + c] = hh;
      W1l[n*32 + c] = f2bf(v - bf2f(hh));
    }
  } else {
    int k0 = (bid-9)*32;
    for (int i=t;i<4096;i+=256){ int k=i>>7, n=i&127; buf[k][n] = W4[(size_t)(k0+k)*128 + n]; }
    __syncthreads();
    int n = t>>1, kq = t&1;
    #pragma unroll
    for (int kk=0;kk<16;kk++){
      int k = kq*16 + kk;
      float v = buf[k][n];
      u16 hh = f2bf(v);
      W4h[(size_t)n*128 + k0 + k] = hh;
      W4l[(size_t)n*128 + k0 + k] = f2bf(v - bf2f(hh));
    }
  }
}

// ---------- fused 2D forward DFT: y[b][c][h][w] -> F2[b*32+c][kyi][kxri] ----
__global__ __launch_bounds__(256) void k_dft2d(const float* __restrict__ y, float* __restrict__ F2){
  __shared__ float xs[128][132];
  __shared__ float T1[128][28];
  __shared__ float P2[4800];     // [kx][ri][hg][kyi(25)]
  int t = threadIdx.x;
  int bc = blockIdx.x;           // 256
  for (int i=t;i<16384;i+=256){ xs[i>>7][i&127] = y[(size_t)bc*16384 + i]; }
  __syncthreads();
  // phase A: W-direction, 12 kx modes, register rotators
  {
    int h = t>>1, wg = t&1;
    float cr[12], ci[12], aR[12], aI[12], stc[12], sts[12];
    #pragma unroll
    for (int k=0;k<12;k++){
      aR[k]=0.f; aI[k]=0.f;
      cr[k] = ((k&1)&&wg)? -1.f : 1.f; ci[k]=0.f;
      float s,c; sincospif(k*(1.0f/64.0f), &s, &c); stc[k]=c; sts[k]=s;
    }
    const float* xrow = &xs[h][wg*64];
    for (int q=0;q<16;q++){
      float4 xq = *reinterpret_cast<const float4*>(&xrow[q*4]);
      float xa[4] = {xq.x,xq.y,xq.z,xq.w};
      #pragma unroll
      for (int e=0;e<4;e++){
        float xw = xa[e];
        #pragma unroll
        for (int k=0;k<12;k++){
          aR[k] += xw*cr[k];
          aI[k] -= xw*ci[k];
          float nc = cr[k]*stc[k] - ci[k]*sts[k];
          ci[k]    = cr[k]*sts[k] + ci[k]*stc[k];
          cr[k] = nc;
        }
      }
    }
    #pragma unroll
    for (int k=0;k<12;k++){
      aR[k] += __shfl_xor(aR[k], 1);
      aI[k] += __shfl_xor(aI[k], 1);
    }
    __syncthreads();
    #pragma unroll
    for (int q=0;q<6;q++){
      int k = wg*6+q;
      T1[h][2*k]   = aR[k];
      T1[h][2*k+1] = aI[k];
    }
  }
  __syncthreads();
  // phase B: H-direction, 24 ky modes
  {
    int kyi = t&31, hg = t>>5;
    if (kyi < 24){
      int ky = (kyi<12)? kyi : kyi+104;
      float aR[12], aI[12];
      #pragma unroll
      for (int k=0;k<12;k++){ aR[k]=0.f; aI[k]=0.f; }
      float sc,ss; sincospif(ky*(1.0f/64.0f), &ss, &sc);
      float c0,s0; sincospif((float)(ky*hg)*0.25f, &s0, &c0);
      for (int hh=0; hh<16; hh++){
        int h = hg*16+hh;
        float a[24];
        #pragma unroll
        for (int q=0;q<6;q++) *reinterpret_cast<float4*>(&a[q*4]) = *reinterpret_cast<const float4*>(&T1[h][q*4]);
        #pragma unroll
        for (int k=0;k<12;k++){
          aR[k] += a[2*k]*c0 + a[2*k+1]*s0;
          aI[k] += a[2*k+1]*c0 - a[2*k]*s0;
        }
        float nc = c0*sc - s0*ss; s0 = c0*ss + s0*sc; c0 = nc;
      }
      #pragma unroll
      for (int k=0;k<12;k++){
        P2[((k*2+0)*8+hg)*25 + kyi] = aR[k];
        P2[((k*2+1)*8+hg)*25 + kyi] = aI[k];
      }
    }
  }
  __syncthreads();
  for (int j=t; j<576; j+=256){
    int kyi = j/24, col = j%24;
    float s = 0.f;
    #pragma unroll
    for (int hg=0;hg<8;hg++) s += P2[(col*8+hg)*25 + kyi];
    F2[(size_t)bc*576 + kyi*24 + col] = s;
  }
}

// ---------------- mode mix with transposed weights --------------------------
// F2[b*32+c][kyi][kxri] x wT[hf][kym][kx][i][o][ri] -> G[b*32+o][kyi][kxri]
__global__ __launch_bounds__(256) void k_mix(const float* __restrict__ F2, const float* __restrict__ wTl,
                     float* __restrict__ G){
  __shared__ float fr[12][33], fi[12][33];
  int t=threadIdx.x;
  int kyi = blockIdx.x>>3, b = blockIdx.x&7;   // 192 blocks
  for (int j=t; j<768; j+=256){
    int c = j/24, col = j%24;
    float v = F2[((size_t)(b*32+c)*24 + kyi)*24 + col];
    if (col&1) fi[col>>1][c] = v; else fr[col>>1][c] = v;
  }
  __syncthreads();
  int hf = kyi<12?0:1, kym = kyi<12?kyi:kyi-12;
  const float* wb = wTl + (size_t)(hf*12+kym)*24576;
  for (int j=t; j<384; j+=256){
    int o = j&31, kx = j>>5;
    const float* wp = wb + kx*2048 + o*2;
    float gr=0.f, gi=0.f;
    #pragma unroll 8
    for (int i=0;i<32;i++){
      float2 wv = *reinterpret_cast<const float2*>(&wp[i*64]);
      float ar = fr[kx][i], ai = fi[kx][i];
      gr += ar*wv.x - ai*wv.y;
      gi += ar*wv.y + ai*wv.x;
    }
    size_t gidx = ((size_t)(b*32+o)*24 + kyi)*24 + kx*2;
    G[gidx] = gr; G[gidx+1] = gi;
  }
}

// ------------- inverse H-DFT: G[bo][kyi][kxri] -> S1[bo][h][kxri] ----------
__global__ __launch_bounds__(256) void k_idfth(const float* __restrict__ G, float* __restrict__ S1){
  __shared__ float Gs[24][28];
  int t=threadIdx.x;
  int bo = blockIdx.x;          // 256
  for (int i=t;i<576;i+=256){ Gs[i/24][i%24] = G[(size_t)bo*576 + i]; }
  __syncthreads();
  int h = t>>1, hf = t&1;
  float aR[12], aI[12];
  #pragma unroll
  for (int k=0;k<12;k++){ aR[k]=0.f; aI[k]=0.f; }
  float sc,ss; sincospif(h*(1.0f/64.0f), &ss, &sc);
  float c0,s0;
  if (hf==0){ c0=1.f; s0=0.f; }
  else { sincospif((float)(116*h)*(1.0f/64.0f), &s0, &c0); }
  for (int j=0;j<12;j++){
    int kyi = hf*12 + j;
    float a[24];
    #pragma unroll
    for (int q=0;q<6;q++) *reinterpret_cast<float4*>(&a[q*4]) = *reinterpret_cast<const float4*>(&Gs[kyi][q*4]);
    #pragma unroll
    for (int k=0;k<12;k++){
      aR[k] += a[2*k]*c0 - a[2*k+1]*s0;
      aI[k] += a[2*k]*s0 + a[2*k+1]*c0;
    }
    float nc = c0*sc - s0*ss; s0 = c0*ss + s0*sc; c0 = nc;
  }
  #pragma unroll
  for (int k=0;k<12;k++){
    aR[k] += __shfl_xor(aR[k], 1);
    aI[k] += __shfl_xor(aI[k], 1);
  }
  float* dst = S1 + ((size_t)bo*128 + h)*24;
  #pragma unroll
  for (int q=0;q<6;q++){
    int k = hf*6 + q;
    dst[2*k]   = aR[k]*(1.0f/16384.0f);
    dst[2*k+1] = aI[k]*(1.0f/16384.0f);
  }
}

// --------- combine: inverse-W DFT + conv1x1 + bias terms + GELU -------------
// LAST=1 emits y as bf16 hi/lo [pix][32] for the MFMA head.
template<int LAST>
__global__ __launch_bounds__(256) void k_combine(const float* __restrict__ yin, const float* __restrict__ S1,
                         const float* __restrict__ x,
                         const float* __restrict__ wWl, const float* __restrict__ wbl,
                         const float* __restrict__ bWl, const float* __restrict__ bbl,
                         const float* __restrict__ cWl, const float* __restrict__ cbl,
                         float* __restrict__ yout,
                         u16* __restrict__ yh, u16* __restrict__ yl){
  __shared__ float ysT[128][33];
  int t=threadIdx.x;
  int b = blockIdx.x>>7, h = blockIdx.x&127;
  for (int i=t;i<4096;i+=256){ int c=i>>7, w=i&127;
    ysT[w][c] = yin[(((size_t)(b*32+c))*128+h)*128+w]; }
  __syncthreads();
  int w = t&127;
  int og = __builtin_amdgcn_readfirstlane(t>>7);   // wave-uniform 0/1
  float xv[32];
  #pragma unroll
  for (int c=0;c<32;c++) xv[c] = ysT[w][c];
  float ct[12], st[12];
  ct[0]=1.f; st[0]=0.f;
  float c1,s1v; sincospif(w*(1.0f/64.0f), &s1v, &c1);
  #pragma unroll
  for (int k=0;k<11;k++){ ct[k+1] = ct[k]*c1 - st[k]*s1v; st[k+1] = ct[k]*s1v + st[k]*c1; }
  float gx = h*(1.0f/127.0f), gy = w*(1.0f/127.0f);
  float4 xm = *reinterpret_cast<const float4*>(x + (((size_t)(b*128+h))*128+w)*4);
  float m1=xm.y, m2=xm.z, m3=xm.w;
  const float* wo  = wWl + og*512;                 // [16][32]
  const float* s1o = S1 + (size_t)b*98304 + (size_t)og*16*3072 + h*24;
  float accv[16];
  #pragma unroll
  for (int oi=0;oi<16;oi++){
    int o = og*16+oi;
    float bse = wbl[o] + bbl[o] + cbl[o] + gx*bWl[o*2] + gy*bWl[o*2+1]
              + m1*cWl[o*3] + m2*cWl[o*3+1] + m3*cWl[o*3+2];
    const float* sp = s1o + (size_t)oi*3072;
    float spec = sp[0];
    #pragma unroll
    for (int kx=1;kx<12;kx++) spec += 2.0f*(sp[2*kx]*ct[kx] - sp[2*kx+1]*st[kx]);
    accv[oi] = bse + spec;
  }
  #pragma unroll
  for (int c=0;c<32;c++){
    float xc = xv[c];
    #pragma unroll
    for (int oi=0;oi<16;oi++) accv[oi] += wo[oi*32+c]*xc;
  }
  if constexpr (!LAST){
    #pragma unroll
    for (int oi=0;oi<16;oi++){
      int o = og*16+oi;
      yout[(((size_t)(b*32+o))*128+h)*128+w] = gelu_f(accv[oi]);
    }
  } else {
    __syncthreads();     // all ysT reads done (xv in regs); reuse ysT as [w][o]
    #pragma unroll
    for (int oi=0;oi<16;oi++) ysT[w][og*16+oi] = gelu_f(accv[oi]);
    __syncthreads();
    int wr = t>>1, hf2 = t&1;
    size_t pix = (size_t)b*16384 + h*128 + wr;
    ushort8v h8a, l8a, h8b, l8b;
    #pragma unroll
    for (int q=0;q<8;q++){
      float v = ysT[wr][hf2*16 + q];
      u16 hh = f2bf(v);
      h8a[q] = hh; l8a[q] = f2bf(v - bf2f(hh));
      float v2 = ysT[wr][hf2*16 + 8 + q];
      u16 hh2 = f2bf(v2);
      h8b[q] = hh2; l8b[q] = f2bf(v2 - bf2f(hh2));
    }
    *reinterpret_cast<ushort8v*>(yh + pix*32 + hf2*16)     = h8a;
    *reinterpret_cast<ushort8v*>(yh + pix*32 + hf2*16 + 8) = h8b;
    *reinterpret_cast<ushort8v*>(yl + pix*32 + hf2*16)     = l8a;
    *reinterpret_cast<ushort8v*>(yl + pix*32 + hf2*16 + 8) = l8b;
  }
}

// ---- fully fused head: fc1+fc3+fc4+fc5 via MFMA bf16x3 -> out[p] ----------
__global__ __launch_bounds__(256) void k_headm(
    const u16* __restrict__ Yh, const u16* __restrict__ Yl,     // [pix][32]
    const u16* __restrict__ W1h, const u16* __restrict__ W1l,   // [256 n1][32 k]
    const float* __restrict__ b1,
    const u16* __restrict__ W3h, const u16* __restrict__ W3l,   // [128 n3][256 k]
    const float* __restrict__ b3,
    const u16* __restrict__ W4h, const u16* __restrict__ W4l,   // [128 n4][128 k]
    const float* __restrict__ b4, const float* __restrict__ w5,
    const float* __restrict__ b5, float* __restrict__ out){
  // LDS union: stage A = Ach/Acl/W3ch/W3cl [128][40] (20480 u16);
  //            stage B = A2h/A2l [128][136]          (34816 u16)
  __shared__ u16 smem[34816];
  __shared__ float b1s[256];
  __shared__ float b3s[128], b4s[128], w5s[128];
  u16* Ach  = smem;
  u16* Acl  = smem + 5120;
  u16* W3ch = smem + 10240;
  u16* W3cl = smem + 15360;
  int t = threadIdx.x;
  int wv = t>>6, lane = t&63, lr = lane&15, lg = lane>>4;
  int P0 = blockIdx.x*128;
  b1s[t] = b1[t];
  if (t<128){ b3s[t]=b3[t]; b4s[t]=b4[t]; w5s[t]=w5[t]; }
  int wn3 = wv>>1, wp = wv&1;
  int p0w = wv*32;
  // Y fragments: kt-invariant, straight from global (coalesced 16B/lane)
  short8v ybh[2], ybl[2];
  #pragma unroll
  for (int j=0;j<2;j++){
    size_t p = (size_t)P0 + p0w + j*16 + lr;
    ybh[j] = *reinterpret_cast<const short8v*>(Yh + p*32 + lg*8);
    ybl[j] = *reinterpret_cast<const short8v*>(Yl + p*32 + lg*8);
  }
  f32x4 acc3[4][4];
  #pragma unroll
  for (int i=0;i<4;i++)
    #pragma unroll
    for (int j=0;j<4;j++) acc3[i][j] = (f32x4){0.f,0.f,0.f,0.f};
  __syncthreads();   // biases visible

  for (int kt=0; kt<8; ++kt){
    // ---- issue W3 chunk loads early ----
    int srow = t>>1, soff = (t&1)*16;
    const u16* g3h = W3h + (size_t)srow*256 + kt*32 + soff;
    const u16* g3l = W3l + (size_t)srow*256 + kt*32 + soff;
    ushort8v wh0 = *reinterpret_cast<const ushort8v*>(g3h);
    ushort8v wh1 = *reinterpret_cast<const ushort8v*>(g3h+8);
    ushort8v wl0 = *reinterpret_cast<const ushort8v*>(g3l);
    ushort8v wl1 = *reinterpret_cast<const ushort8v*>(g3l+8);
    // ---- fc1: A1 chunk [128p][32n1] ----
    f32x4 a1[2][2];
    #pragma unroll
    for (int i=0;i<2;i++)
      #pragma unroll
      for (int j=0;j<2;j++) a1[i][j] = (f32x4){0.f,0.f,0.f,0.f};
    #pragma unroll
    for (int i=0;i<2;i++){
      int n1 = kt*32 + i*16 + lr;
      short8v w1f = *reinterpret_cast<const short8v*>(W1h + (size_t)n1*32 + lg*8);
      short8v w1g = *reinterpret_cast<const short8v*>(W1l + (size_t)n1*32 + lg*8);
      #pragma unroll
      for (int j=0;j<2;j++){
        a1[i][j] = __builtin_amdgcn_mfma_f32_16x16x32_bf16(w1f, ybh[j], a1[i][j], 0,0,0);
        a1[i][j] = __builtin_amdgcn_mfma_f32_16x16x32_bf16(w1f, ybl[j], a1[i][j], 0,0,0);
        a1[i][j] = __builtin_amdgcn_mfma_f32_16x16x32_bf16(w1g, ybh[j], a1[i][j], 0,0,0);
      }
    }
    // gelu + split -> Ac chunk ([p][n1loc]); D rows=n1(4lg+reg), cols=p(lr)
    #pragma unroll
    for (int i=0;i<2;i++){
      int n1b = kt*32 + i*16 + 4*lg;
      #pragma unroll
      for (int j=0;j<2;j++){
        int p = p0w + j*16 + lr;
        ushort4v hv, lv;
        #pragma unroll
        for (int r=0;r<4;r++){
          float v = gelu_f(a1[i][j][r] + b1s[n1b+r]);
          u16 hh = f2bf(v);
          hv[r] = hh; lv[r] = f2bf(v - bf2f(hh));
        }
        *reinterpret_cast<ushort4v*>(&Ach[p*40 + i*16+4*lg]) = hv;
        *reinterpret_cast<ushort4v*>(&Acl[p*40 + i*16+4*lg]) = lv;
      }
    }
    // ---- write W3 chunk ----
    *reinterpret_cast<ushort8v*>(&W3ch[srow*40 + soff])   = wh0;
    *reinterpret_cast<ushort8v*>(&W3ch[srow*40 + soff+8]) = wh1;
    *reinterpret_cast<ushort8v*>(&W3cl[srow*40 + soff])   = wl0;
    *reinterpret_cast<ushort8v*>(&W3cl[srow*40 + soff+8]) = wl1;
    __syncthreads();
    // ---- fc3 accumulate ----
    short8v abh[4], abl[4];
    #pragma unroll
    for (int j=0;j<4;j++){
      int pb = wp*64 + j*16 + lr;
      abh[j] = *reinterpret_cast<const short8v*>(&Ach[pb*40 + lg*8]);
      abl[j] = *reinterpret_cast<const short8v*>(&Acl[pb*40 + lg*8]);
    }
    #pragma unroll
    for (int i=0;i<4;i++){
      int n3 = wn3*64 + i*16 + lr;
      short8v w3f = *reinterpret_cast<const short8v*>(&W3ch[n3*40 + lg*8]);
      short8v w3g = *reinterpret_cast<const short8v*>(&W3cl[n3*40 + lg*8]);
      #pragma unroll
      for (int j=0;j<4;j++){
        acc3[i][j] = __builtin_amdgcn_mfma_f32_16x16x32_bf16(w3f, abh[j], acc3[i][j], 0,0,0);
        acc3[i][j] = __builtin_amdgcn_mfma_f32_16x16x32_bf16(w3f, abl[j], acc3[i][j], 0,0,0);
        acc3[i][j] = __builtin_amdgcn_mfma_f32_16x16x32_bf16(w3g, abh[j], acc3[i][j], 0,0,0);
      }
    }
    __syncthreads();
  }
  // ---- stage B: gelu(fc3)+split -> A2 LDS [128p][128n3] hi/lo ----
  u16* A2h = smem;
  u16* A2l = smem + 17408;
  #pragma unroll
  for (int i=0;i<4;i++){
    int n3b = wn3*64 + i*16 + 4*lg;
    #pragma unroll
    for (int j=0;j<4;j++){
      int p = wp*64 + j*16 + lr;
      ushort4v hv, lv;
      #pragma unroll
      for (int r=0;r<4;r++){
        float v = gelu_f(acc3[i][j][r] + b3s[n3b+r]);
        u16 hh = f2bf(v);
        hv[r] = hh; lv[r] = f2bf(v - bf2f(hh));
      }
      *reinterpret_cast<ushort4v*>(&A2h[p*136 + n3b]) = hv;
      *reinterpret_cast<ushort4v*>(&A2l[p*136 + n3b]) = lv;
    }
  }
  __syncthreads();
  // ---- fc4: wave owns p-quarter (32 p), full n4=128; K=128 in 4 steps ----
  f32x4 acc4[8][2];
  #pragma unroll
  for (int i=0;i<8;i++){ acc4[i][0]=(f32x4){0.f,0.f,0.f,0.f}; acc4[i][1]=(f32x4){0.f,0.f,0.f,0.f}; }
  #pragma unroll
  for (int ks=0; ks<4; ++ks){
    short8v p2h[2], p2l[2];
    #pragma unroll
    for (int j=0;j<2;j++){
      int p = wv*32 + j*16 + lr;
      p2h[j] = *reinterpret_cast<const short8v*>(&A2h[p*136 + ks*32 + lg*8]);
      p2l[j] = *reinterpret_cast<const short8v*>(&A2l[p*136 + ks*32 + lg*8]);
    }
    #pragma unroll
    for (int i2=0;i2<8;i2++){
      int n4 = i2*16 + lr;
      short8v w4f = *reinterpret_cast<const short8v*>(W4h + (size_t)n4*128 + ks*32 + lg*8);
      short8v w4g = *reinterpret_cast<const short8v*>(W4l + (size_t)n4*128 + ks*32 + lg*8);
      #pragma unroll
      for (int j=0;j<2;j++){
        acc4[i2][j] = __builtin_amdgcn_mfma_f32_16x16x32_bf16(w4f, p2h[j], acc4[i2][j], 0,0,0);
        acc4[i2][j] = __builtin_amdgcn_mfma_f32_16x16x32_bf16(w4f, p2l[j], acc4[i2][j], 0,0,0);
        acc4[i2][j] = __builtin_amdgcn_mfma_f32_16x16x32_bf16(w4g, p2h[j], acc4[i2][j], 0,0,0);
      }
    }
  }
  // ---- fc5: dot with w5 + b4, reduce over lg, write out ----
  float b5v = b5[0];
  float part0 = 0.f, part1 = 0.f;
  #pragma unroll
  for (int i2=0;i2<8;i2++){
    #pragma unroll
    for (int r=0;r<4;r++){
      int n4 = i2*16 + 4*lg + r;
      float wv5 = w5s[n4], bb4 = b4s[n4];
      part0 += (acc4[i2][0][r] + bb4)*wv5;
      part1 += (acc4[i2][1][r] + bb4)*wv5;
    }
  }
  part0 += __shfl_xor(part0, 16); part0 += __shfl_xor(part0, 32);
  part1 += __shfl_xor(part1, 16); part1 += __shfl_xor(part1, 32);
  if (lg==0){
    out[P0 + wv*32 + lr]      = part0 + b5v;
    out[P0 + wv*32 + 16 + lr] = part1 + b5v;
  }
}

extern "C" void kernel_launch(void* const* d_in, const int* in_sizes, int n_in,
                              void* d_out, int out_size, void* d_ws, size_t ws_size,
                              hipStream_t stream){
  const float* x     = (const float*)d_in[0];
  const float* fc0_W = (const float*)d_in[1];
  const float* fc0_b = (const float*)d_in[2];
  const float* spec_w= (const float*)d_in[3];
  const float* wW    = (const float*)d_in[4];
  const float* wb    = (const float*)d_in[5];
  const float* bW    = (const float*)d_in[6];
  const float* bb    = (const float*)d_in[7];
  const float* cW    = (const float*)d_in[8];
  const float* cb    = (const float*)d_in[9];
  const float* fc1_W = (const float*)d_in[10];
  const float* fc1_b = (const float*)d_in[11];
  const float* fc3_W = (const float*)d_in[12];
  const float* fc3_b = (const float*)d_in[13];
  const float* fc4_W = (const float*)d_in[14];
  const float* fc4_b = (const float*)d_in[15];
  const float* fc5_W = (const float*)d_in[16];
  const float* fc5_b = (const float*)d_in[17];
  float* out = (float*)d_out;
  float* ws  = (float*)d_ws;

  float* y_a = ws;                         // 4,194,304
  float* y_b = y_a + 4194304;              // 4,194,304
  float* wT  = y_b + 4194304;              // 3,538,944
  float* F2  = wT + 3538944;               //   147,456
  float* G   = F2 + 147456;                //   147,456
  float* S1  = G  + 147456;                //   786,432
  float* WP  = S1 + 786432;                // head weight prep (57,344 floats)
  u16*   W1h = (u16*)WP;                   //  8,192 u16
  u16*   W1l = W1h + 8192;
  u16*   W3h = W1l + 8192;                 // 32,768 u16
  u16*   W3l = W3h + 32768;
  u16*   W4h = W3l + 32768;                // 16,384 u16
  u16*   W4l = W4h + 16384;
  // overlays (stream-ordered): final layer (l=5, odd) reads y_b, so y_a is free
  u16*   Yhh  = (u16*)y_a;                 // final y hi [pix][32]
  u16*   Yll_ = (u16*)y_a + 4194304;       // final y lo

  k_fc0<<<512,256,0,stream>>>(x, fc0_W, fc0_b, y_a);
  k_wtrans<<<288,256,0,stream>>>(spec_w, wT);
  k_wprep<<<13,256,0,stream>>>(fc1_W, fc3_W, fc4_W, W1h, W1l, W3h, W3l, W4h, W4l);

  for (int l=0;l<NL;l++){
    float* yin  = (l&1)? y_b : y_a;
    float* yout = (l&1)? y_a : y_b;
    k_dft2d<<<256,256,0,stream>>>(yin, F2);
    k_mix<<<192,256,0,stream>>>(F2, wT + (size_t)l*589824, G);
    k_idfth<<<256,256,0,stream>>>(G, S1);
    if (l < NL-1){
      k_combine<0><<<1024,256,0,stream>>>(yin, S1, x,
                                     wW + (size_t)l*1024, wb + (size_t)l*32,
                                     bW + (size_t)l*64,  bb + (size_t)l*32,
                                     cW + (size_t)l*96,  cb + (size_t)l*32,
                                     yout, nullptr, nullptr);
    } else {
      k_combine<1><<<1024,256,0,stream>>>(yin, S1, x,
                                     wW + (size_t)l*1024, wb + (size_t)l*32,
                                     bW + (size_t)l*64,  bb + (size_t)l*32,
                                     cW + (size_t)l*96,  cb + (size_t)l*32,
                                     nullptr, Yhh, Yll_);
    }
  }

  k_headm<<<1024,256,0,stream>>>(Yhh, Yll_, W1h, W1l, fc1_b, W3h, W3l, fc3_b,
                                 W4h, W4l, fc4_b, fc5_W, fc5_b, out);
}

// Round 8
// 615.607 us; speedup vs baseline: 1.1619x; 1.0032x over previous
//
#include <hip/hip_runtime.h>
#include <math.h>

// FNO2d: B=8, H=W=128, WIDTH=32, MODES=12, NL=6
// Spectral conv via partial DFT. W-DFT fused into producers (fc0/combine);
// layer = {dfth, mixid, combine2}. Head fc1..fc5 fused MFMA (bf16 hi/lo x3).

#define NL 6

typedef unsigned short u16;
typedef __attribute__((ext_vector_type(8))) short short8v;
typedef __attribute__((ext_vector_type(8))) unsigned short ushort8v;
typedef __attribute__((ext_vector_type(4))) unsigned short ushort4v;
typedef __attribute__((ext_vector_type(4))) float f32x4;

// A&S 7.1.26 erf: max abs err 1.5e-7, branchless
__device__ __forceinline__ float gelu_f(float x){
  float z  = x*0.70710678118654752f;
  float az = fabsf(z);
  float t  = 1.0f/(1.0f + 0.3275911f*az);
  float p  = t*(0.254829592f + t*(-0.284496736f + t*(1.421413741f +
             t*(-1.453152027f + t*1.061405429f))));
  float e  = __expf(-z*z);
  float er = copysignf(1.0f - p*e, z);
  return 0.5f*x*(1.0f + er);
}
__device__ __forceinline__ u16 f2bf(float x){
  unsigned u = __float_as_uint(x);
  u += 0x7FFF + ((u>>16)&1);
  return (u16)(u>>16);
}
__device__ __forceinline__ float bf2f(u16 h){
  return __uint_as_float(((unsigned)h)<<16);
}

// ---- fc0 + fused W-DFT: x -> y[B,32,H,W]; also F1[bc][h][24] ---------------
__global__ __launch_bounds__(256) void k_fc0f(const float* __restrict__ x,
                      const float* __restrict__ W, const float* __restrict__ b,
                      float* __restrict__ y, float* __restrict__ F1){
  __shared__ float Ws[128];
  __shared__ float bs[32];
  __shared__ float ys2[2][32][132];
  int t = threadIdx.x;
  if (t < 128) Ws[t] = W[t];
  if (t < 32)  bs[t] = b[t];
  __syncthreads();
  int pix = blockIdx.x*256 + t;
  float4 xv = *reinterpret_cast<const float4*>(x + (size_t)pix*4);
  int bb = pix >> 14, hw = pix & 16383;
  int r = t>>7, w = t&127;
  float* yp = y + (size_t)bb*32*16384 + hw;
  #pragma unroll
  for (int c=0;c<32;c++){
    float acc = bs[c] + xv.x*Ws[c] + xv.y*Ws[32+c] + xv.z*Ws[64+c] + xv.w*Ws[96+c];
    yp[(size_t)c*16384] = acc;
    ys2[r][c][w] = acc;
  }
  __syncthreads();
  // W-DFT: thread (c2 = t>>3, wq = t&7) covers 16 w per row
  int c2 = t>>3, wq = t&7;
  float stc[12], sts[12];
  #pragma unroll
  for (int k=0;k<12;k++){ float s,c; sincospif(k*(1.0f/64.0f), &s, &c); stc[k]=c; sts[k]=s; }
  int gr0 = blockIdx.x*2;
  #pragma unroll
  for (int r2=0;r2<2;r2++){
    float cr[12], ci[12], aR[12], aI[12];
    #pragma unroll
    for (int k=0;k<12;k++){
      float s,c; sincospif((float)(k*wq)*0.25f, &s, &c);
      cr[k]=c; ci[k]=s; aR[k]=0.f; aI[k]=0.f;
    }
    const float* rowp = &ys2[r2][c2][wq*16];
    #pragma unroll
    for (int q=0;q<4;q++){
      float4 xq = *reinterpret_cast<const float4*>(rowp + q*4);
      float xa[4]={xq.x,xq.y,xq.z,xq.w};
      #pragma unroll
      for (int e=0;e<4;e++){
        float xw = xa[e];
        #pragma unroll
        for (int k=0;k<12;k++){
          aR[k] += xw*cr[k];
          aI[k] -= xw*ci[k];
          float nc = cr[k]*stc[k] - ci[k]*sts[k];
          ci[k]    = cr[k]*sts[k] + ci[k]*stc[k];
          cr[k] = nc;
        }
      }
    }
    #pragma unroll
    for (int k=0;k<12;k++){
      aR[k] += __shfl_xor(aR[k],1); aR[k] += __shfl_xor(aR[k],2); aR[k] += __shfl_xor(aR[k],4);
      aI[k] += __shfl_xor(aI[k],1); aI[k] += __shfl_xor(aI[k],2); aI[k] += __shfl_xor(aI[k],4);
    }
    if (wq==0){
      int g = gr0 + r2; int b2 = g>>7, h2 = g&127;
      float* dst = F1 + ((size_t)(b2*32+c2)*128 + h2)*24;
      #pragma unroll
      for (int k=0;k<12;k++){ dst[2*k] = aR[k]; dst[2*k+1] = aI[k]; }
    }
  }
}

// ------- one-time weight transpose: spec_w[l][hf][i][o][kym][kx][ri] ------
// -> wT[l][hf][kym][kx][o][i][ri]   (o-major for k_mixid)
__global__ __launch_bounds__(256) void k_wtrans(const float* __restrict__ w, float* __restrict__ wT){
  __shared__ float buf[16][32][25];
  int t=threadIdx.x;
  int beta = blockIdx.x;            // 6*2*12*2 = 288
  int l = beta/48, r = beta%48;
  int hf = r/24; int r2 = r%24;
  int kym = r2>>1; int i0 = (r2&1)*16;
  const float* src = w + (size_t)l*589824 + (size_t)hf*294912 + kym*24;
  float* dst = wT + (size_t)l*589824 + (size_t)hf*294912 + (size_t)kym*24576;
  for (int j=t; j<12288; j+=256){
    int i = j/768, rem = j%768, o = rem/24, kxri = rem%24;
    buf[i][o][kxri] = src[(size_t)(i0+i)*9216 + o*288 + kxri];
  }
  __syncthreads();
  for (int j=t; j<12288; j+=256){
    int kx = j>>10, rem = j&1023, i = rem>>6, orr = rem&63, o = orr>>1, ri = orr&1;
    dst[(size_t)kx*2048 + o*64 + (i0+i)*2 + ri] = buf[i][o][kx*2+ri];
  }
}

// ------- head weight prep: W1->[n1][32] h/l; W3->[n3][256] h/l; W4->[n4][128] h/l
__global__ __launch_bounds__(256) void k_wprep(const float* __restrict__ W1, const float* __restrict__ W3,
                       const float* __restrict__ W4,
                       u16* __restrict__ W1h, u16* __restrict__ W1l,
                       u16* __restrict__ W3h, u16* __restrict__ W3l,
                       u16* __restrict__ W4h, u16* __restrict__ W4l){
  __shared__ float buf[32][132];
  int t = threadIdx.x, bid = blockIdx.x;   // 13 blocks
  if (bid < 8){
    int k0 = bid*32;
    for (int i=t;i<4096;i+=256){ int k=i>>7, n=i&127; buf[k][n] = W3[(size_t)(k0+k)*128 + n]; }
    __syncthreads();
    int n = t>>1, kq = t&1;
    #pragma unroll
    for (int kk=0;kk<16;kk++){
      int k = kq*16 + kk;
      float v = buf[k][n];
      u16 hh = f2bf(v);
      W3h[(size_t)n*256 + k0 + k] = hh;
      W3l[(size_t)n*256 + k0 + k] = f2bf(v - bf2f(hh));
    }
  } else if (bid == 8){
    int n = t;
    #pragma unroll
    for (int c=0;c<32;c++){
      float v = W1[(size_t)c*256 + n];
      u16 hh = f2bf(v);
      W1h[n*32 + c] = hh;
      W1l[n*32 + c] = f2bf(v - bf2f(hh));
    }
  } else {
    int k0 = (bid-9)*32;
    for (int i=t;i<4096;i+=256){ int k=i>>7, n=i&127; buf[k][n] = W4[(size_t)(k0+k)*128 + n]; }
    __syncthreads();
    int n = t>>1, kq = t&1;
    #pragma unroll
    for (int kk=0;kk<16;kk++){
      int k = kq*16 + kk;
      float v = buf[k][n];
      u16 hh = f2bf(v);
      W4h[(size_t)n*128 + k0 + k] = hh;
      W4l[(size_t)n*128 + k0 + k] = f2bf(v - bf2f(hh));
    }
  }
}

// ------- H-DFT: F1[bc][h][24] -> F2[b][kyi][col][32 c] ----------------------
__global__ __launch_bounds__(256) void k_dfth(const float* __restrict__ F1, float* __restrict__ F2){
  __shared__ float fs[128][25];
  __shared__ float twc[128], tws[128];
  int t=threadIdx.x;
  if (t<128){ float s,c; sincospif(t*(1.0f/64.0f), &s, &c); twc[t]=c; tws[t]=s; }
  int bc = blockIdx.x;                            // 256 blocks
  int b = bc>>5, c = bc&31;
  const float* src = F1 + (size_t)bc*3072;
  for (int i=t;i<3072;i+=256){ int h=i/24, col=i%24; fs[h][col] = src[i]; }
  __syncthreads();
  for (int j=t;j<576;j+=256){
    int col = j%24, kyi = j/24, kx = col>>1, ri = col&1;
    int ky = kyi<12 ? kyi : kyi+104;
    float acc=0.f;
    if (ri==0){
      for (int h=0;h<128;h++){ int m=(ky*h)&127; acc += fs[h][2*kx]*twc[m] + fs[h][2*kx+1]*tws[m]; }
    } else {
      for (int h=0;h<128;h++){ int m=(ky*h)&127; acc += fs[h][2*kx+1]*twc[m] - fs[h][2*kx]*tws[m]; }
    }
    F2[(((size_t)b*24 + kyi)*24 + col)*32 + c] = acc;
  }
}

// ------- fused mode-mix + inverse H-DFT: F2 x wT2 -> S1[bo][h][24] ----------
__global__ __launch_bounds__(256) void k_mixid(const float* __restrict__ F2, const float* __restrict__ wTl,
                      float* __restrict__ S1){
  __shared__ float Gs[24][28];
  int t=threadIdx.x;
  int bo = blockIdx.x;            // 256 = b*32+o
  int b = bo>>5, o = bo&31;
  for (int j=t; j<288; j+=256){
    int kx = j%12, kyi = j/12;
    int hf = kyi<12?0:1, kym = kyi<12?kyi:kyi-12;
    const float* fp = F2 + (((size_t)b*24 + kyi)*24 + 2*kx)*32;
    const float* wp = wTl + (size_t)(hf*12+kym)*24576 + kx*2048 + o*64;
    float gr=0.f, gi=0.f;
    #pragma unroll 8
    for (int i=0;i<32;i++){
      float2 wv = *reinterpret_cast<const float2*>(wp + 2*i);
      float ar = fp[i], ai = fp[32+i];
      gr += ar*wv.x - ai*wv.y;
      gi += ar*wv.y + ai*wv.x;
    }
    Gs[kyi][2*kx] = gr; Gs[kyi][2*kx+1] = gi;
  }
  __syncthreads();
  // inverse H-DFT (proven body)
  int h = t>>1, hf = t&1;
  float aR[12], aI[12];
  #pragma unroll
  for (int k=0;k<12;k++){ aR[k]=0.f; aI[k]=0.f; }
  float sc,ss; sincospif(h*(1.0f/64.0f), &ss, &sc);
  float c0,s0;
  if (hf==0){ c0=1.f; s0=0.f; }
  else { sincospif((float)(116*h)*(1.0f/64.0f), &s0, &c0); }
  for (int j=0;j<12;j++){
    int kyi = hf*12 + j;
    float a[24];
    #pragma unroll
    for (int q=0;q<6;q++) *reinterpret_cast<float4*>(&a[4*q]) = *reinterpret_cast<const float4*>(&Gs[kyi][4*q]);
    #pragma unroll
    for (int k=0;k<12;k++){
      aR[k] += a[2*k]*c0 - a[2*k+1]*s0;
      aI[k] += a[2*k]*s0 + a[2*k+1]*c0;
    }
    float nc = c0*sc - s0*ss; s0 = c0*ss + s0*sc; c0 = nc;
  }
  #pragma unroll
  for (int k=0;k<12;k++){
    aR[k] += __shfl_xor(aR[k], 1);
    aI[k] += __shfl_xor(aI[k], 1);
  }
  float* dst = S1 + ((size_t)bo*128 + h)*24;
  #pragma unroll
  for (int q=0;q<6;q++){
    int k = hf*6 + q;
    dst[2*k]   = aR[k]*(1.0f/16384.0f);
    dst[2*k+1] = aI[k]*(1.0f/16384.0f);
  }
}

// --------- combine2: inverse-W DFT + conv1x1 + bias + GELU, then fused
//           forward W-DFT of the OUTPUT -> F1 (next layer). LAST: bf16 emit.
template<int LAST>
__global__ __launch_bounds__(256) void k_combine2(const float* __restrict__ yin, const float* __restrict__ S1,
                         const float* __restrict__ x,
                         const float* __restrict__ wWl, const float* __restrict__ wbl,
                         const float* __restrict__ bWl, const float* __restrict__ bbl,
                         const float* __restrict__ cWl, const float* __restrict__ cbl,
                         float* __restrict__ yout, float* __restrict__ F1,
                         u16* __restrict__ yh, u16* __restrict__ yl){
  __shared__ float ysT[128][33];            // 4224 floats
  float (*ysT2)[132] = (float(*)[132])ysT;  // alias: [32 o][132] (4224 floats)
  int t=threadIdx.x;
  int b = blockIdx.x>>7, h = blockIdx.x&127;
  for (int i=t;i<4096;i+=256){ int c=i>>7, w=i&127;
    ysT[w][c] = yin[(((size_t)(b*32+c))*128+h)*128+w]; }
  __syncthreads();
  int w = t&127;
  int og = __builtin_amdgcn_readfirstlane(t>>7);   // wave-uniform 0/1
  float xv[32];
  #pragma unroll
  for (int c=0;c<32;c++) xv[c] = ysT[w][c];
  float ct[12], st[12];
  ct[0]=1.f; st[0]=0.f;
  float c1,s1v; sincospif(w*(1.0f/64.0f), &s1v, &c1);
  #pragma unroll
  for (int k=0;k<11;k++){ ct[k+1] = ct[k]*c1 - st[k]*s1v; st[k+1] = ct[k]*s1v + st[k]*c1; }
  float gx = h*(1.0f/127.0f), gy = w*(1.0f/127.0f);
  float4 xm = *reinterpret_cast<const float4*>(x + (((size_t)(b*128+h))*128+w)*4);
  float m1=xm.y, m2=xm.z, m3=xm.w;
  const float* wo  = wWl + og*512;                 // [16][32]
  const float* s1o = S1 + (size_t)b*98304 + (size_t)og*16*3072 + h*24;
  float accv[16];
  #pragma unroll
  for (int oi=0;oi<16;oi++){
    int o = og*16+oi;
    float bse = wbl[o] + bbl[o] + cbl[o] + gx*bWl[o*2] + gy*bWl[o*2+1]
              + m1*cWl[o*3] + m2*cWl[o*3+1] + m3*cWl[o*3+2];
    const float* sp = s1o + (size_t)oi*3072;
    float spec = sp[0];
    #pragma unroll
    for (int kx=1;kx<12;kx++) spec += 2.0f*(sp[2*kx]*ct[kx] - sp[2*kx+1]*st[kx]);
    accv[oi] = bse + spec;
  }
  #pragma unroll
  for (int c=0;c<32;c++){
    float xc = xv[c];
    #pragma unroll
    for (int oi=0;oi<16;oi++) accv[oi] += wo[oi*32+c]*xc;
  }
  __syncthreads();            // all ysT reads done (xv in regs) before overwrite
  #pragma unroll
  for (int oi=0;oi<16;oi++){
    float g = gelu_f(accv[oi]);
    accv[oi] = g;
    ysT2[og*16+oi][w] = g;    // [o][w] for W-DFT / emit
  }
  __syncthreads();
  if constexpr (!LAST){
    #pragma unroll
    for (int oi=0;oi<16;oi++){
      int o = og*16+oi;
      yout[(((size_t)(b*32+o))*128+h)*128+w] = accv[oi];
    }
    // forward W-DFT of output row -> F1[b][o][h][24]
    int c2 = t>>3, wq = t&7;
    float cr[12], ci[12], aR[12], aI[12], stc[12], sts[12];
    #pragma unroll
    for (int k=0;k<12;k++){
      float s,c; sincospif(k*(1.0f/64.0f), &s, &c); stc[k]=c; sts[k]=s;
      sincospif((float)(k*wq)*0.25f, &s, &c);
      cr[k]=c; ci[k]=s; aR[k]=0.f; aI[k]=0.f;
    }
    const float* rowp = &ysT2[c2][wq*16];
    #pragma unroll
    for (int q=0;q<4;q++){
      float4 xq = *reinterpret_cast<const float4*>(rowp + q*4);
      float xa[4]={xq.x,xq.y,xq.z,xq.w};
      #pragma unroll
      for (int e=0;e<4;e++){
        float xw = xa[e];
        #pragma unroll
        for (int k=0;k<12;k++){
          aR[k] += xw*cr[k];
          aI[k] -= xw*ci[k];
          float nc = cr[k]*stc[k] - ci[k]*sts[k];
          ci[k]    = cr[k]*sts[k] + ci[k]*stc[k];
          cr[k] = nc;
        }
      }
    }
    #pragma unroll
    for (int k=0;k<12;k++){
      aR[k] += __shfl_xor(aR[k],1); aR[k] += __shfl_xor(aR[k],2); aR[k] += __shfl_xor(aR[k],4);
      aI[k] += __shfl_xor(aI[k],1); aI[k] += __shfl_xor(aI[k],2); aI[k] += __shfl_xor(aI[k],4);
    }
    if (wq==0){
      float* dst = F1 + ((size_t)(b*32+c2)*128 + h)*24;
      #pragma unroll
      for (int k=0;k<12;k++){ dst[2*k] = aR[k]; dst[2*k+1] = aI[k]; }
    }
  } else {
    int wr = t>>1, hf2 = t&1;
    size_t pix = (size_t)b*16384 + h*128 + wr;
    ushort8v h8a, l8a, h8b, l8b;
    #pragma unroll
    for (int q=0;q<8;q++){
      float v = ysT2[hf2*16 + q][wr];
      u16 hh = f2bf(v);
      h8a[q] = hh; l8a[q] = f2bf(v - bf2f(hh));
      float v2 = ysT2[hf2*16 + 8 + q][wr];
      u16 hh2 = f2bf(v2);
      h8b[q] = hh2; l8b[q] = f2bf(v2 - bf2f(hh2));
    }
    *reinterpret_cast<ushort8v*>(yh + pix*32 + hf2*16)     = h8a;
    *reinterpret_cast<ushort8v*>(yh + pix*32 + hf2*16 + 8) = h8b;
    *reinterpret_cast<ushort8v*>(yl + pix*32 + hf2*16)     = l8a;
    *reinterpret_cast<ushort8v*>(yl + pix*32 + hf2*16 + 8) = l8b;
  }
}

// ---- fully fused head: fc1+fc3+fc4+fc5 via MFMA bf16x3, 64-pixel blocks ----
__global__ __launch_bounds__(256) void k_headm(
    const u16* __restrict__ Yh, const u16* __restrict__ Yl,     // [pix][32]
    const u16* __restrict__ W1h, const u16* __restrict__ W1l,   // [256 n1][32 k]
    const float* __restrict__ b1,
    const u16* __restrict__ W3h, const u16* __restrict__ W3l,   // [128 n3][256 k]
    const float* __restrict__ b3,
    const u16* __restrict__ W4h, const u16* __restrict__ W4l,   // [128 n4][128 k]
    const float* __restrict__ b4, const float* __restrict__ w5,
    const float* __restrict__ b5, float* __restrict__ out){
  // LDS union: stage A = Ach[64][40],Acl,W3ch[128][40],W3cl = 15360 u16
  //            stage B = A2h[64][136],A2l = 17408 u16
  __shared__ u16 smem[17408];
  __shared__ float b1s[256];
  __shared__ float b3s[128], b4s[128], w5s[128];
  __shared__ float part2[2][64];
  u16* Ach  = smem;
  u16* Acl  = smem + 2560;
  u16* W3ch = smem + 5120;
  u16* W3cl = smem + 10240;
  int t = threadIdx.x;
  int wv = t>>6, lane = t&63, lr = lane&15, lg = lane>>4;
  int P0 = blockIdx.x*64;
  b1s[t] = b1[t];
  if (t<128){ b3s[t]=b3[t]; b4s[t]=b4[t]; w5s[t]=w5[t]; }
  int wn3 = wv>>1, wp = wv&1;
  // Y fragments: kt-invariant, straight from global
  short8v ybh, ybl;
  {
    size_t p = (size_t)P0 + wv*16 + lr;
    ybh = *reinterpret_cast<const short8v*>(Yh + p*32 + lg*8);
    ybl = *reinterpret_cast<const short8v*>(Yl + p*32 + lg*8);
  }
  f32x4 acc3[4][2];
  #pragma unroll
  for (int i=0;i<4;i++){ acc3[i][0]=(f32x4){0,0,0,0}; acc3[i][1]=(f32x4){0,0,0,0}; }
  __syncthreads();

  for (int kt=0; kt<8; ++kt){
    // issue W3 chunk loads early
    int srow = t>>1, soff = (t&1)*16;
    const u16* g3h = W3h + (size_t)srow*256 + kt*32 + soff;
    const u16* g3l = W3l + (size_t)srow*256 + kt*32 + soff;
    ushort8v wh0 = *reinterpret_cast<const ushort8v*>(g3h);
    ushort8v wh1 = *reinterpret_cast<const ushort8v*>(g3h+8);
    ushort8v wl0 = *reinterpret_cast<const ushort8v*>(g3l);
    ushort8v wl1 = *reinterpret_cast<const ushort8v*>(g3l+8);
    // fc1: A1 chunk [64p][32n1]; wave owns 16 p
    f32x4 a1[2];
    a1[0]=(f32x4){0,0,0,0}; a1[1]=(f32x4){0,0,0,0};
    #pragma unroll
    for (int i=0;i<2;i++){
      int n1 = kt*32 + i*16 + lr;
      short8v w1f = *reinterpret_cast<const short8v*>(W1h + (size_t)n1*32 + lg*8);
      short8v w1g = *reinterpret_cast<const short8v*>(W1l + (size_t)n1*32 + lg*8);
      a1[i] = __builtin_amdgcn_mfma_f32_16x16x32_bf16(w1f, ybh, a1[i], 0,0,0);
      a1[i] = __builtin_amdgcn_mfma_f32_16x16x32_bf16(w1f, ybl, a1[i], 0,0,0);
      a1[i] = __builtin_amdgcn_mfma_f32_16x16x32_bf16(w1g, ybh, a1[i], 0,0,0);
    }
    // gelu+split -> Ac [p][n1loc]; D rows=n1(4lg+r), cols=p(lr)
    #pragma unroll
    for (int i=0;i<2;i++){
      int n1b = kt*32 + i*16 + 4*lg;
      int p = wv*16 + lr;
      ushort4v hv, lv;
      #pragma unroll
      for (int r=0;r<4;r++){
        float v = gelu_f(a1[i][r] + b1s[n1b+r]);
        u16 hh = f2bf(v);
        hv[r] = hh; lv[r] = f2bf(v - bf2f(hh));
      }
      *reinterpret_cast<ushort4v*>(&Ach[p*40 + i*16+4*lg]) = hv;
      *reinterpret_cast<ushort4v*>(&Acl[p*40 + i*16+4*lg]) = lv;
    }
    // write W3 chunk
    *reinterpret_cast<ushort8v*>(&W3ch[srow*40 + soff])   = wh0;
    *reinterpret_cast<ushort8v*>(&W3ch[srow*40 + soff+8]) = wh1;
    *reinterpret_cast<ushort8v*>(&W3cl[srow*40 + soff])   = wl0;
    *reinterpret_cast<ushort8v*>(&W3cl[srow*40 + soff+8]) = wl1;
    __syncthreads();
    // fc3 accumulate: wave owns n3-half (wn3) x p-half (wp)
    short8v abh[2], abl[2];
    #pragma unroll
    for (int j=0;j<2;j++){
      int pb = wp*32 + j*16 + lr;
      abh[j] = *reinterpret_cast<const short8v*>(&Ach[pb*40 + lg*8]);
      abl[j] = *reinterpret_cast<const short8v*>(&Acl[pb*40 + lg*8]);
    }
    #pragma unroll
    for (int i=0;i<4;i++){
      int n3 = wn3*64 + i*16 + lr;
      short8v w3f = *reinterpret_cast<const short8v*>(&W3ch[n3*40 + lg*8]);
      short8v w3g = *reinterpret_cast<const short8v*>(&W3cl[n3*40 + lg*8]);
      #pragma unroll
      for (int j=0;j<2;j++){
        acc3[i][j] = __builtin_amdgcn_mfma_f32_16x16x32_bf16(w3f, abh[j], acc3[i][j], 0,0,0);
        acc3[i][j] = __builtin_amdgcn_mfma_f32_16x16x32_bf16(w3f, abl[j], acc3[i][j], 0,0,0);
        acc3[i][j] = __builtin_amdgcn_mfma_f32_16x16x32_bf16(w3g, abh[j], acc3[i][j], 0,0,0);
      }
    }
    __syncthreads();
  }
  // stage B: gelu(fc3)+split -> A2 [64p][136] hi/lo
  u16* A2h = smem;
  u16* A2l = smem + 8704;
  #pragma unroll
  for (int i=0;i<4;i++){
    int n3b = wn3*64 + i*16 + 4*lg;
    #pragma unroll
    for (int j=0;j<2;j++){
      int p = wp*32 + j*16 + lr;
      ushort4v hv, lv;
      #pragma unroll
      for (int r=0;r<4;r++){
        float v = gelu_f(acc3[i][j][r] + b3s[n3b+r]);
        u16 hh = f2bf(v);
        hv[r] = hh; lv[r] = f2bf(v - bf2f(hh));
      }
      *reinterpret_cast<ushort4v*>(&A2h[p*136 + n3b]) = hv;
      *reinterpret_cast<ushort4v*>(&A2l[p*136 + n3b]) = lv;
    }
  }
  __syncthreads();
  // fc4: wave owns n4-half (wn3) x p-half (wp); K=128 in 4 steps
  f32x4 acc4[4][2];
  #pragma unroll
  for (int i=0;i<4;i++){ acc4[i][0]=(f32x4){0,0,0,0}; acc4[i][1]=(f32x4){0,0,0,0}; }
  #pragma unroll
  for (int ks=0; ks<4; ++ks){
    short8v p2h[2], p2l[2];
    #pragma unroll
    for (int j=0;j<2;j++){
      int p = wp*32 + j*16 + lr;
      p2h[j] = *reinterpret_cast<const short8v*>(&A2h[p*136 + ks*32 + lg*8]);
      p2l[j] = *reinterpret_cast<const short8v*>(&A2l[p*136 + ks*32 + lg*8]);
    }
    #pragma unroll
    for (int i2=0;i2<4;i2++){
      int n4 = wn3*64 + i2*16 + lr;
      short8v w4f = *reinterpret_cast<const short8v*>(W4h + (size_t)n4*128 + ks*32 + lg*8);
      short8v w4g = *reinterpret_cast<const short8v*>(W4l + (size_t)n4*128 + ks*32 + lg*8);
      #pragma unroll
      for (int j=0;j<2;j++){
        acc4[i2][j] = __builtin_amdgcn_mfma_f32_16x16x32_bf16(w4f, p2h[j], acc4[i2][j], 0,0,0);
        acc4[i2][j] = __builtin_amdgcn_mfma_f32_16x16x32_bf16(w4f, p2l[j], acc4[i2][j], 0,0,0);
        acc4[i2][j] = __builtin_amdgcn_mfma_f32_16x16x32_bf16(w4g, p2h[j], acc4[i2][j], 0,0,0);
      }
    }
  }
  // fc5: dot with w5 (+b4), reduce over lg, cross-wave partial via LDS
  #pragma unroll
  for (int j=0;j<2;j++){
    float part = 0.f;
    #pragma unroll
    for (int i2=0;i2<4;i2++){
      #pragma unroll
      for (int r=0;r<4;r++){
        int n4 = wn3*64 + i2*16 + 4*lg + r;
        part += (acc4[i2][j][r] + b4s[n4]) * w5s[n4];
      }
    }
    part += __shfl_xor(part, 16); part += __shfl_xor(part, 32);
    if (lg==0) part2[wn3][wp*32 + j*16 + lr] = part;
  }
  __syncthreads();
  if (t<64) out[P0 + t] = part2[0][t] + part2[1][t] + b5[0];
}

extern "C" void kernel_launch(void* const* d_in, const int* in_sizes, int n_in,
                              void* d_out, int out_size, void* d_ws, size_t ws_size,
                              hipStream_t stream){
  const float* x     = (const float*)d_in[0];
  const float* fc0_W = (const float*)d_in[1];
  const float* fc0_b = (const float*)d_in[2];
  const float* spec_w= (const float*)d_in[3];
  const float* wW    = (const float*)d_in[4];
  const float* wb    = (const float*)d_in[5];
  const float* bW    = (const float*)d_in[6];
  const float* bb    = (const float*)d_in[7];
  const float* cW    = (const float*)d_in[8];
  const float* cb    = (const float*)d_in[9];
  const float* fc1_W = (const float*)d_in[10];
  const float* fc1_b = (const float*)d_in[11];
  const float* fc3_W = (const float*)d_in[12];
  const float* fc3_b = (const float*)d_in[13];
  const float* fc4_W = (const float*)d_in[14];
  const float* fc4_b = (const float*)d_in[15];
  const float* fc5_W = (const float*)d_in[16];
  const float* fc5_b = (const float*)d_in[17];
  float* out = (float*)d_out;
  float* ws  = (float*)d_ws;

  float* y_a = ws;                         // 4,194,304
  float* y_b = y_a + 4194304;              // 4,194,304
  float* wT  = y_b + 4194304;              // 3,538,944
  float* F2  = wT + 3538944;               //   147,456
  float* S1  = F2 + 147456;                //   786,432
  float* F1  = S1 + 786432;                //   786,432
  float* WP  = F1 + 786432;                // head weight prep
  u16*   W1h = (u16*)WP;                   //  8,192 u16
  u16*   W1l = W1h + 8192;
  u16*   W3h = W1l + 8192;                 // 32,768 u16
  u16*   W3l = W3h + 32768;
  u16*   W4h = W3l + 32768;                // 16,384 u16
  u16*   W4l = W4h + 16384;
  // overlays: final layer (l=5, odd) reads y_b, so y_a is free
  u16*   Yhh  = (u16*)y_a;                 // final y hi [pix][32]
  u16*   Yll_ = (u16*)y_a + 4194304;       // final y lo

  k_fc0f<<<512,256,0,stream>>>(x, fc0_W, fc0_b, y_a, F1);
  k_wtrans<<<288,256,0,stream>>>(spec_w, wT);
  k_wprep<<<13,256,0,stream>>>(fc1_W, fc3_W, fc4_W, W1h, W1l, W3h, W3l, W4h, W4l);

  for (int l=0;l<NL;l++){
    float* yin  = (l&1)? y_b : y_a;
    float* yout = (l&1)? y_a : y_b;
    k_dfth<<<256,256,0,stream>>>(F1, F2);
    k_mixid<<<256,256,0,stream>>>(F2, wT + (size_t)l*589824, S1);
    if (l < NL-1){
      k_combine2<0><<<1024,256,0,stream>>>(yin, S1, x,
                                     wW + (size_t)l*1024, wb + (size_t)l*32,
                                     bW + (size_t)l*64,  bb + (size_t)l*32,
                                     cW + (size_t)l*96,  cb + (size_t)l*32,
                                     yout, F1, nullptr, nullptr);
    } else {
      k_combine2<1><<<1024,256,0,stream>>>(yin, S1, x,
                                     wW + (size_t)l*1024, wb + (size_t)l*32,
                                     bW + (size_t)l*64,  bb + (size_t)l*32,
                                     cW + (size_t)l*96,  cb + (size_t)l*32,
                                     nullptr, nullptr, Yhh, Yll_);
    }
  }

  k_headm<<<2048,256,0,stream>>>(Yhh, Yll_, W1h, W1l, fc1_b, W3h, W3l, fc3_b,
                                 W4h, W4l, fc4_b, fc5_W, fc5_b, out);
}

// Round 9
// 479.636 us; speedup vs baseline: 1.4912x; 1.2835x over previous
//
#include <hip/hip_runtime.h>
#include <math.h>

// FNO2d: B=8, H=W=128, WIDTH=32, MODES=12, NL=6
// Spectral conv via partial DFT. W-DFT fused into producers (fc0/combine);
// layer = {dfth, mixid, combine2}. Head fc1..fc5 fused MFMA (bf16 hi/lo x3).

#define NL 6

typedef unsigned short u16;
typedef __attribute__((ext_vector_type(8))) short short8v;
typedef __attribute__((ext_vector_type(8))) unsigned short ushort8v;
typedef __attribute__((ext_vector_type(4))) unsigned short ushort4v;
typedef __attribute__((ext_vector_type(4))) float f32x4;

// A&S 7.1.26 erf, branchless, raw v_rcp (max abs err ~1.5e-7)
__device__ __forceinline__ float gelu_f(float x){
  float z  = x*0.70710678118654752f;
  float az = fabsf(z);
  float t  = __builtin_amdgcn_rcpf(fmaf(0.3275911f, az, 1.0f));
  float p  = t*(0.254829592f + t*(-0.284496736f + t*(1.421413741f +
             t*(-1.453152027f + t*1.061405429f))));
  float e  = __expf(-z*z);
  float er = copysignf(fmaf(-p, e, 1.0f), z);
  return 0.5f*x*(1.0f + er);
}
__device__ __forceinline__ u16 f2bf(float x){
  unsigned u = __float_as_uint(x);
  u += 0x7FFF + ((u>>16)&1);
  return (u16)(u>>16);
}
__device__ __forceinline__ float bf2f(u16 h){
  return __uint_as_float(((unsigned)h)<<16);
}
// truncation split: hi = top16(v), lo = bf16_trunc(v - hi). Error class 2^-17.
__device__ __forceinline__ void split2(float v, u16 &hh, u16 &ll){
  unsigned u = __float_as_uint(v);
  hh = (u16)(u>>16);
  float lo = v - __uint_as_float(u & 0xFFFF0000u);
  ll = (u16)(__float_as_uint(lo)>>16);
}

// ---- fc0 + fused W-DFT: x -> y[B,32,H,W]; also F1[bc][h][24] ---------------
__global__ __launch_bounds__(256) void k_fc0f(const float* __restrict__ x,
                      const float* __restrict__ W, const float* __restrict__ b,
                      float* __restrict__ y, float* __restrict__ F1){
  __shared__ float Ws[128];
  __shared__ float bs[32];
  __shared__ float ys2[2][32][132];
  int t = threadIdx.x;
  if (t < 128) Ws[t] = W[t];
  if (t < 32)  bs[t] = b[t];
  __syncthreads();
  int pix = blockIdx.x*256 + t;
  float4 xv = *reinterpret_cast<const float4*>(x + (size_t)pix*4);
  int bb = pix >> 14, hw = pix & 16383;
  int r = t>>7, w = t&127;
  float* yp = y + (size_t)bb*32*16384 + hw;
  #pragma unroll
  for (int c=0;c<32;c++){
    float acc = bs[c] + xv.x*Ws[c] + xv.y*Ws[32+c] + xv.z*Ws[64+c] + xv.w*Ws[96+c];
    yp[(size_t)c*16384] = acc;
    ys2[r][c][w] = acc;
  }
  __syncthreads();
  int c2 = t>>3, wq = t&7;
  float stc[12], sts[12];
  #pragma unroll
  for (int k=0;k<12;k++){ float s,c; sincospif(k*(1.0f/64.0f), &s, &c); stc[k]=c; sts[k]=s; }
  int gr0 = blockIdx.x*2;
  #pragma unroll
  for (int r2=0;r2<2;r2++){
    float cr[12], ci[12], aR[12], aI[12];
    #pragma unroll
    for (int k=0;k<12;k++){
      float s,c; sincospif((float)(k*wq)*0.25f, &s, &c);
      cr[k]=c; ci[k]=s; aR[k]=0.f; aI[k]=0.f;
    }
    const float* rowp = &ys2[r2][c2][wq*16];
    #pragma unroll
    for (int q=0;q<4;q++){
      float4 xq = *reinterpret_cast<const float4*>(rowp + q*4);
      float xa[4]={xq.x,xq.y,xq.z,xq.w};
      #pragma unroll
      for (int e=0;e<4;e++){
        float xw = xa[e];
        #pragma unroll
        for (int k=0;k<12;k++){
          aR[k] += xw*cr[k];
          aI[k] -= xw*ci[k];
          float nc = cr[k]*stc[k] - ci[k]*sts[k];
          ci[k]    = cr[k]*sts[k] + ci[k]*stc[k];
          cr[k] = nc;
        }
      }
    }
    #pragma unroll
    for (int k=0;k<12;k++){
      aR[k] += __shfl_xor(aR[k],1); aR[k] += __shfl_xor(aR[k],2); aR[k] += __shfl_xor(aR[k],4);
      aI[k] += __shfl_xor(aI[k],1); aI[k] += __shfl_xor(aI[k],2); aI[k] += __shfl_xor(aI[k],4);
    }
    if (wq==0){
      int g = gr0 + r2; int b2 = g>>7, h2 = g&127;
      float* dst = F1 + ((size_t)(b2*32+c2)*128 + h2)*24;
      #pragma unroll
      for (int k=0;k<12;k++){ dst[2*k] = aR[k]; dst[2*k+1] = aI[k]; }
    }
  }
}

// ------- one-time weight transpose -> wT[l][hf][kym][kx][o][i][ri] ---------
__global__ __launch_bounds__(256) void k_wtrans(const float* __restrict__ w, float* __restrict__ wT){
  __shared__ float buf[16][32][25];
  int t=threadIdx.x;
  int beta = blockIdx.x;            // 288
  int l = beta/48, r = beta%48;
  int hf = r/24; int r2 = r%24;
  int kym = r2>>1; int i0 = (r2&1)*16;
  const float* src = w + (size_t)l*589824 + (size_t)hf*294912 + kym*24;
  float* dst = wT + (size_t)l*589824 + (size_t)hf*294912 + (size_t)kym*24576;
  for (int j=t; j<12288; j+=256){
    int i = j/768, rem = j%768, o = rem/24, kxri = rem%24;
    buf[i][o][kxri] = src[(size_t)(i0+i)*9216 + o*288 + kxri];
  }
  __syncthreads();
  for (int j=t; j<12288; j+=256){
    int kx = j>>10, rem = j&1023, i = rem>>6, orr = rem&63, o = orr>>1, ri = orr&1;
    dst[(size_t)kx*2048 + o*64 + (i0+i)*2 + ri] = buf[i][o][kx*2+ri];
  }
}

// ------- head weight prep ---------------------------------------------------
__global__ __launch_bounds__(256) void k_wprep(const float* __restrict__ W1, const float* __restrict__ W3,
                       const float* __restrict__ W4,
                       u16* __restrict__ W1h, u16* __restrict__ W1l,
                       u16* __restrict__ W3h, u16* __restrict__ W3l,
                       u16* __restrict__ W4h, u16* __restrict__ W4l){
  __shared__ float buf[32][132];
  int t = threadIdx.x, bid = blockIdx.x;   // 13 blocks
  if (bid < 8){
    int k0 = bid*32;
    for (int i=t;i<4096;i+=256){ int k=i>>7, n=i&127; buf[k][n] = W3[(size_t)(k0+k)*128 + n]; }
    __syncthreads();
    int n = t>>1, kq = t&1;
    #pragma unroll
    for (int kk=0;kk<16;kk++){
      int k = kq*16 + kk;
      float v = buf[k][n];
      u16 hh = f2bf(v);
      W3h[(size_t)n*256 + k0 + k] = hh;
      W3l[(size_t)n*256 + k0 + k] = f2bf(v - bf2f(hh));
    }
  } else if (bid == 8){
    int n = t;
    #pragma unroll
    for (int c=0;c<32;c++){
      float v = W1[(size_t)c*256 + n];
      u16 hh = f2bf(v);
      W1h[n*32 + c] = hh;
      W1l[n*32 + c] = f2bf(v - bf2f(hh));
    }
  } else {
    int k0 = (bid-9)*32;
    for (int i=t;i<4096;i+=256){ int k=i>>7, n=i&127; buf[k][n] = W4[(size_t)(k0+k)*128 + n]; }
    __syncthreads();
    int n = t>>1, kq = t&1;
    #pragma unroll
    for (int kk=0;kk<16;kk++){
      int k = kq*16 + kk;
      float v = buf[k][n];
      u16 hh = f2bf(v);
      W4h[(size_t)n*128 + k0 + k] = hh;
      W4l[(size_t)n*128 + k0 + k] = f2bf(v - bf2f(hh));
    }
  }
}

// ------- H-DFT: F1[bc][h][24] -> F2[b][kyi][col][32 c] ----------------------
// 512 threads; 288 compute threads, register rotator, float2 LDS reads.
__global__ __launch_bounds__(512) void k_dfth(const float* __restrict__ F1, float* __restrict__ F2){
  __shared__ float fs[3072];   // [h][24]
  int t=threadIdx.x;
  int bc = blockIdx.x;                            // 256 blocks
  int b = bc>>5, c = bc&31;
  const float* src = F1 + (size_t)bc*3072;
  for (int i=t;i<3072;i+=512) fs[i] = src[i];
  __syncthreads();
  if (t < 288){
    int kx = t%12, kyi = t/12;
    int ky = (kyi<12)? kyi : kyi+104;
    float cs, ss; sincospif((float)ky*(1.0f/64.0f), &ss, &cs);
    float aR=0.f, aI=0.f;
    #pragma unroll
    for (int hq=0; hq<4; hq++){
      int m0 = (ky*hq*32)&127;
      float c0,s0; sincospif((float)m0*(1.0f/64.0f), &s0, &c0);
      #pragma unroll 8
      for (int hh=0; hh<32; hh++){
        int h = hq*32+hh;
        float2 a = *reinterpret_cast<const float2*>(&fs[h*24 + 2*kx]);
        aR += a.x*c0 + a.y*s0;
        aI += a.y*c0 - a.x*s0;
        float nc = c0*cs - s0*ss; s0 = c0*ss + s0*cs; c0 = nc;
      }
    }
    float* dst = F2 + (((size_t)b*24 + kyi)*24 + 2*kx)*32 + c;
    dst[0]  = aR;
    dst[32] = aI;
  }
}

// ------- fused mode-mix + inverse H-DFT: F2 x wT2 -> S1[bo][h][24] ----------
// 512 threads: mix on 288, idft with 4-lane h split.
__global__ __launch_bounds__(512) void k_mixid(const float* __restrict__ F2, const float* __restrict__ wTl,
                      float* __restrict__ S1){
  __shared__ float Gs[24][28];
  int t=threadIdx.x;
  int bo = blockIdx.x;            // 256 = b*32+o
  int b = bo>>5, o = bo&31;
  if (t < 288){
    int kx = t%12, kyi = t/12;
    int hf = kyi<12?0:1, kym = kyi<12?kyi:kyi-12;
    const float* fp = F2 + (((size_t)b*24 + kyi)*24 + 2*kx)*32;
    const float* wp = wTl + (size_t)(hf*12+kym)*24576 + kx*2048 + o*64;
    float gr=0.f, gi=0.f;
    #pragma unroll 8
    for (int i=0;i<32;i++){
      float2 wv = *reinterpret_cast<const float2*>(wp + 2*i);
      float ar = fp[i], ai = fp[32+i];
      gr += ar*wv.x - ai*wv.y;
      gi += ar*wv.y + ai*wv.x;
    }
    Gs[kyi][2*kx] = gr; Gs[kyi][2*kx+1] = gi;
  }
  __syncthreads();
  // inverse H-DFT: t = h*4 + q; each q handles 6 kyi, shfl-combined
  int h = t>>2, q = t&3;
  float aR[12], aI[12];
  #pragma unroll
  for (int k=0;k<12;k++){ aR[k]=0.f; aI[k]=0.f; }
  float sc,ss; sincospif(h*(1.0f/64.0f), &ss, &sc);
  int ky0 = (q<2)? q*6 : 116 + (q-2)*6;
  float c0,s0;
  { int m0 = (ky0*h)&127; sincospif((float)m0*(1.0f/64.0f), &s0, &c0); }
  #pragma unroll
  for (int j=0;j<6;j++){
    int kyi = q*6 + j;
    float a[24];
    #pragma unroll
    for (int q2=0;q2<6;q2++) *reinterpret_cast<float4*>(&a[4*q2]) = *reinterpret_cast<const float4*>(&Gs[kyi][4*q2]);
    #pragma unroll
    for (int k=0;k<12;k++){
      aR[k] += a[2*k]*c0 - a[2*k+1]*s0;
      aI[k] += a[2*k]*s0 + a[2*k+1]*c0;
    }
    float nc = c0*sc - s0*ss; s0 = c0*ss + s0*sc; c0 = nc;
  }
  #pragma unroll
  for (int k=0;k<12;k++){
    aR[k] += __shfl_xor(aR[k], 1); aR[k] += __shfl_xor(aR[k], 2);
    aI[k] += __shfl_xor(aI[k], 1); aI[k] += __shfl_xor(aI[k], 2);
  }
  float* dst = S1 + ((size_t)bo*128 + h)*24;
  #pragma unroll
  for (int r=0;r<3;r++){
    int k = q*3 + r;
    dst[2*k]   = aR[k]*(1.0f/16384.0f);
    dst[2*k+1] = aI[k]*(1.0f/16384.0f);
  }
}

// --------- combine2 (512 threads): inverse-W DFT + conv1x1 + bias + GELU,
//           then fused forward W-DFT -> F1 (next layer). LAST: bf16 emit.
template<int LAST>
__global__ __launch_bounds__(512) void k_combine2(const float* __restrict__ yin, const float* __restrict__ S1,
                         const float* __restrict__ x,
                         const float* __restrict__ wWl, const float* __restrict__ wbl,
                         const float* __restrict__ bWl, const float* __restrict__ bbl,
                         const float* __restrict__ cWl, const float* __restrict__ cbl,
                         float* __restrict__ yout, float* __restrict__ F1,
                         u16* __restrict__ yh, u16* __restrict__ yl){
  __shared__ float ysT[128][33];            // 4224 floats
  float (*ysT2)[132] = (float(*)[132])ysT;  // alias: [32 o][132]
  int t=threadIdx.x;
  int b = blockIdx.x>>7, h = blockIdx.x&127;
  for (int i=t;i<4096;i+=512){ int c=i>>7, w=i&127;
    ysT[w][c] = yin[(((size_t)(b*32+c))*128+h)*128+w]; }
  __syncthreads();
  int w = t&127;
  int og = __builtin_amdgcn_readfirstlane(t>>7);   // wave-uniform 0..3
  float ct[12], st[12];
  ct[0]=1.f; st[0]=0.f;
  float c1,s1v; sincospif(w*(1.0f/64.0f), &s1v, &c1);
  #pragma unroll
  for (int k=0;k<11;k++){ ct[k+1] = ct[k]*c1 - st[k]*s1v; st[k+1] = ct[k]*s1v + st[k]*c1; }
  float gx = h*(1.0f/127.0f), gy = w*(1.0f/127.0f);
  float4 xm = *reinterpret_cast<const float4*>(x + (((size_t)(b*128+h))*128+w)*4);
  float m1=xm.y, m2=xm.z, m3=xm.w;
  const float* wo  = wWl + og*256;                 // [8][32]
  const float* s1o = S1 + (size_t)b*98304 + (size_t)og*8*3072 + h*24;
  float accv[8];
  #pragma unroll
  for (int oi=0;oi<8;oi++){
    int o = og*8+oi;
    float bse = wbl[o] + bbl[o] + cbl[o] + gx*bWl[o*2] + gy*bWl[o*2+1]
              + m1*cWl[o*3] + m2*cWl[o*3+1] + m3*cWl[o*3+2];
    const float* sp = s1o + (size_t)oi*3072;
    float spec = sp[0];
    #pragma unroll
    for (int kx=1;kx<12;kx++) spec += 2.0f*(sp[2*kx]*ct[kx] - sp[2*kx+1]*st[kx]);
    accv[oi] = bse + spec;
  }
  #pragma unroll
  for (int c=0;c<32;c++){
    float xc = ysT[w][c];
    #pragma unroll
    for (int oi=0;oi<8;oi++) accv[oi] += wo[oi*32+c]*xc;
  }
  __syncthreads();            // all ysT reads done before overwrite
  #pragma unroll
  for (int oi=0;oi<8;oi++){
    float g = gelu_f(accv[oi]);
    accv[oi] = g;
    ysT2[og*8+oi][w] = g;     // [o][w]
  }
  __syncthreads();
  if constexpr (!LAST){
    #pragma unroll
    for (int oi=0;oi<8;oi++){
      int o = og*8+oi;
      yout[(((size_t)(b*32+o))*128+h)*128+w] = accv[oi];
    }
    // forward W-DFT of output rows -> F1[b][o][h][24]; 16 lanes per row
    int c2 = t>>4, wq = t&15;
    float cr[12], ci[12], aR[12], aI[12], stc[12], sts[12];
    #pragma unroll
    for (int k=0;k<12;k++){
      float s,c; sincospif(k*(1.0f/64.0f), &s, &c); stc[k]=c; sts[k]=s;
      sincospif((float)((k*wq)&15)*0.125f, &s, &c);
      cr[k]=c; ci[k]=s; aR[k]=0.f; aI[k]=0.f;
    }
    const float* rowp = &ysT2[c2][wq*8];
    #pragma unroll
    for (int q=0;q<2;q++){
      float4 xq = *reinterpret_cast<const float4*>(rowp + q*4);
      float xa[4]={xq.x,xq.y,xq.z,xq.w};
      #pragma unroll
      for (int e=0;e<4;e++){
        float xw = xa[e];
        #pragma unroll
        for (int k=0;k<12;k++){
          aR[k] += xw*cr[k];
          aI[k] -= xw*ci[k];
          float nc = cr[k]*stc[k] - ci[k]*sts[k];
          ci[k]    = cr[k]*sts[k] + ci[k]*stc[k];
          cr[k] = nc;
        }
      }
    }
    #pragma unroll
    for (int k=0;k<12;k++){
      aR[k] += __shfl_xor(aR[k],1); aR[k] += __shfl_xor(aR[k],2);
      aR[k] += __shfl_xor(aR[k],4); aR[k] += __shfl_xor(aR[k],8);
      aI[k] += __shfl_xor(aI[k],1); aI[k] += __shfl_xor(aI[k],2);
      aI[k] += __shfl_xor(aI[k],4); aI[k] += __shfl_xor(aI[k],8);
    }
    if (wq==0){
      float* dst = F1 + ((size_t)(b*32+c2)*128 + h)*24;
      #pragma unroll
      for (int k=0;k<12;k++){ dst[2*k] = aR[k]; dst[2*k+1] = aI[k]; }
    }
  } else {
    int wr = t>>2, hf4 = t&3;
    size_t pix = (size_t)b*16384 + h*128 + wr;
    ushort8v h8, l8;
    #pragma unroll
    for (int q=0;q<8;q++){
      u16 hh, ll;
      split2(ysT2[hf4*8 + q][wr], hh, ll);
      h8[q] = hh; l8[q] = ll;
    }
    *reinterpret_cast<ushort8v*>(yh + pix*32 + hf4*8) = h8;
    *reinterpret_cast<ushort8v*>(yl + pix*32 + hf4*8) = l8;
  }
}

// ---- fully fused head: fc1+fc3+fc4+fc5 via MFMA bf16x3, 64-pixel blocks ----
__global__ __launch_bounds__(256) void k_headm(
    const u16* __restrict__ Yh, const u16* __restrict__ Yl,     // [pix][32]
    const u16* __restrict__ W1h, const u16* __restrict__ W1l,   // [256 n1][32 k]
    const float* __restrict__ b1,
    const u16* __restrict__ W3h, const u16* __restrict__ W3l,   // [128 n3][256 k]
    const float* __restrict__ b3,
    const u16* __restrict__ W4h, const u16* __restrict__ W4l,   // [128 n4][128 k]
    const float* __restrict__ b4, const float* __restrict__ w5,
    const float* __restrict__ b5, float* __restrict__ out){
  __shared__ u16 smem[17408];
  __shared__ float b1s[256];
  __shared__ float b3s[128], b4s[128], w5s[128];
  __shared__ float part2[2][64];
  u16* Ach  = smem;
  u16* Acl  = smem + 2560;
  u16* W3ch = smem + 5120;
  u16* W3cl = smem + 10240;
  int t = threadIdx.x;
  int wv = t>>6, lane = t&63, lr = lane&15, lg = lane>>4;
  int P0 = blockIdx.x*64;
  b1s[t] = b1[t];
  if (t<128){ b3s[t]=b3[t]; b4s[t]=b4[t]; w5s[t]=w5[t]; }
  int wn3 = wv>>1, wp = wv&1;
  short8v ybh, ybl;
  {
    size_t p = (size_t)P0 + wv*16 + lr;
    ybh = *reinterpret_cast<const short8v*>(Yh + p*32 + lg*8);
    ybl = *reinterpret_cast<const short8v*>(Yl + p*32 + lg*8);
  }
  f32x4 acc3[4][2];
  #pragma unroll
  for (int i=0;i<4;i++){ acc3[i][0]=(f32x4){0,0,0,0}; acc3[i][1]=(f32x4){0,0,0,0}; }
  __syncthreads();

  for (int kt=0; kt<8; ++kt){
    int srow = t>>1, soff = (t&1)*16;
    const u16* g3h = W3h + (size_t)srow*256 + kt*32 + soff;
    const u16* g3l = W3l + (size_t)srow*256 + kt*32 + soff;
    ushort8v wh0 = *reinterpret_cast<const ushort8v*>(g3h);
    ushort8v wh1 = *reinterpret_cast<const ushort8v*>(g3h+8);
    ushort8v wl0 = *reinterpret_cast<const ushort8v*>(g3l);
    ushort8v wl1 = *reinterpret_cast<const ushort8v*>(g3l+8);
    f32x4 a1[2];
    a1[0]=(f32x4){0,0,0,0}; a1[1]=(f32x4){0,0,0,0};
    #pragma unroll
    for (int i=0;i<2;i++){
      int n1 = kt*32 + i*16 + lr;
      short8v w1f = *reinterpret_cast<const short8v*>(W1h + (size_t)n1*32 + lg*8);
      short8v w1g = *reinterpret_cast<const short8v*>(W1l + (size_t)n1*32 + lg*8);
      a1[i] = __builtin_amdgcn_mfma_f32_16x16x32_bf16(w1f, ybh, a1[i], 0,0,0);
      a1[i] = __builtin_amdgcn_mfma_f32_16x16x32_bf16(w1f, ybl, a1[i], 0,0,0);
      a1[i] = __builtin_amdgcn_mfma_f32_16x16x32_bf16(w1g, ybh, a1[i], 0,0,0);
    }
    #pragma unroll
    for (int i=0;i<2;i++){
      int n1b = kt*32 + i*16 + 4*lg;
      int p = wv*16 + lr;
      ushort4v hv, lv;
      #pragma unroll
      for (int r=0;r<4;r++){
        float v = gelu_f(a1[i][r] + b1s[n1b+r]);
        u16 hh, ll; split2(v, hh, ll);
        hv[r] = hh; lv[r] = ll;
      }
      *reinterpret_cast<ushort4v*>(&Ach[p*40 + i*16+4*lg]) = hv;
      *reinterpret_cast<ushort4v*>(&Acl[p*40 + i*16+4*lg]) = lv;
    }
    *reinterpret_cast<ushort8v*>(&W3ch[srow*40 + soff])   = wh0;
    *reinterpret_cast<ushort8v*>(&W3ch[srow*40 + soff+8]) = wh1;
    *reinterpret_cast<ushort8v*>(&W3cl[srow*40 + soff])   = wl0;
    *reinterpret_cast<ushort8v*>(&W3cl[srow*40 + soff+8]) = wl1;
    __syncthreads();
    short8v abh[2], abl[2];
    #pragma unroll
    for (int j=0;j<2;j++){
      int pb = wp*32 + j*16 + lr;
      abh[j] = *reinterpret_cast<const short8v*>(&Ach[pb*40 + lg*8]);
      abl[j] = *reinterpret_cast<const short8v*>(&Acl[pb*40 + lg*8]);
    }
    #pragma unroll
    for (int i=0;i<4;i++){
      int n3 = wn3*64 + i*16 + lr;
      short8v w3f = *reinterpret_cast<const short8v*>(&W3ch[n3*40 + lg*8]);
      short8v w3g = *reinterpret_cast<const short8v*>(&W3cl[n3*40 + lg*8]);
      #pragma unroll
      for (int j=0;j<2;j++){
        acc3[i][j] = __builtin_amdgcn_mfma_f32_16x16x32_bf16(w3f, abh[j], acc3[i][j], 0,0,0);
        acc3[i][j] = __builtin_amdgcn_mfma_f32_16x16x32_bf16(w3f, abl[j], acc3[i][j], 0,0,0);
        acc3[i][j] = __builtin_amdgcn_mfma_f32_16x16x32_bf16(w3g, abh[j], acc3[i][j], 0,0,0);
      }
    }
    __syncthreads();
  }
  u16* A2h = smem;
  u16* A2l = smem + 8704;
  #pragma unroll
  for (int i=0;i<4;i++){
    int n3b = wn3*64 + i*16 + 4*lg;
    #pragma unroll
    for (int j=0;j<2;j++){
      int p = wp*32 + j*16 + lr;
      ushort4v hv, lv;
      #pragma unroll
      for (int r=0;r<4;r++){
        float v = gelu_f(acc3[i][j][r] + b3s[n3b+r]);
        u16 hh, ll; split2(v, hh, ll);
        hv[r] = hh; lv[r] = ll;
      }
      *reinterpret_cast<ushort4v*>(&A2h[p*136 + n3b]) = hv;
      *reinterpret_cast<ushort4v*>(&A2l[p*136 + n3b]) = lv;
    }
  }
  __syncthreads();
  f32x4 acc4[4][2];
  #pragma unroll
  for (int i=0;i<4;i++){ acc4[i][0]=(f32x4){0,0,0,0}; acc4[i][1]=(f32x4){0,0,0,0}; }
  #pragma unroll
  for (int ks=0; ks<4; ++ks){
    short8v p2h[2], p2l[2];
    #pragma unroll
    for (int j=0;j<2;j++){
      int p = wp*32 + j*16 + lr;
      p2h[j] = *reinterpret_cast<const short8v*>(&A2h[p*136 + ks*32 + lg*8]);
      p2l[j] = *reinterpret_cast<const short8v*>(&A2l[p*136 + ks*32 + lg*8]);
    }
    #pragma unroll
    for (int i2=0;i2<4;i2++){
      int n4 = wn3*64 + i2*16 + lr;
      short8v w4f = *reinterpret_cast<const short8v*>(W4h + (size_t)n4*128 + ks*32 + lg*8);
      short8v w4g = *reinterpret_cast<const short8v*>(W4l + (size_t)n4*128 + ks*32 + lg*8);
      #pragma unroll
      for (int j=0;j<2;j++){
        acc4[i2][j] = __builtin_amdgcn_mfma_f32_16x16x32_bf16(w4f, p2h[j], acc4[i2][j], 0,0,0);
        acc4[i2][j] = __builtin_amdgcn_mfma_f32_16x16x32_bf16(w4f, p2l[j], acc4[i2][j], 0,0,0);
        acc4[i2][j] = __builtin_amdgcn_mfma_f32_16x16x32_bf16(w4g, p2h[j], acc4[i2][j], 0,0,0);
      }
    }
  }
  #pragma unroll
  for (int j=0;j<2;j++){
    float part = 0.f;
    #pragma unroll
    for (int i2=0;i2<4;i2++){
      #pragma unroll
      for (int r=0;r<4;r++){
        int n4 = wn3*64 + i2*16 + 4*lg + r;
        part += (acc4[i2][j][r] + b4s[n4]) * w5s[n4];
      }
    }
    part += __shfl_xor(part, 16); part += __shfl_xor(part, 32);
    if (lg==0) part2[wn3][wp*32 + j*16 + lr] = part;
  }
  __syncthreads();
  if (t<64) out[P0 + t] = part2[0][t] + part2[1][t] + b5[0];
}

extern "C" void kernel_launch(void* const* d_in, const int* in_sizes, int n_in,
                              void* d_out, int out_size, void* d_ws, size_t ws_size,
                              hipStream_t stream){
  const float* x     = (const float*)d_in[0];
  const float* fc0_W = (const float*)d_in[1];
  const float* fc0_b = (const float*)d_in[2];
  const float* spec_w= (const float*)d_in[3];
  const float* wW    = (const float*)d_in[4];
  const float* wb    = (const float*)d_in[5];
  const float* bW    = (const float*)d_in[6];
  const float* bb    = (const float*)d_in[7];
  const float* cW    = (const float*)d_in[8];
  const float* cb    = (const float*)d_in[9];
  const float* fc1_W = (const float*)d_in[10];
  const float* fc1_b = (const float*)d_in[11];
  const float* fc3_W = (const float*)d_in[12];
  const float* fc3_b = (const float*)d_in[13];
  const float* fc4_W = (const float*)d_in[14];
  const float* fc4_b = (const float*)d_in[15];
  const float* fc5_W = (const float*)d_in[16];
  const float* fc5_b = (const float*)d_in[17];
  float* out = (float*)d_out;
  float* ws  = (float*)d_ws;

  float* y_a = ws;                         // 4,194,304
  float* y_b = y_a + 4194304;              // 4,194,304
  float* wT  = y_b + 4194304;              // 3,538,944
  float* F2  = wT + 3538944;               //   147,456
  float* S1  = F2 + 147456;                //   786,432
  float* F1  = S1 + 786432;                //   786,432
  float* WP  = F1 + 786432;
  u16*   W1h = (u16*)WP;
  u16*   W1l = W1h + 8192;
  u16*   W3h = W1l + 8192;
  u16*   W3l = W3h + 32768;
  u16*   W4h = W3l + 32768;
  u16*   W4l = W4h + 16384;
  u16*   Yhh  = (u16*)y_a;                 // final y hi [pix][32] (l=5 reads y_b)
  u16*   Yll_ = (u16*)y_a + 4194304;

  k_fc0f<<<512,256,0,stream>>>(x, fc0_W, fc0_b, y_a, F1);
  k_wtrans<<<288,256,0,stream>>>(spec_w, wT);
  k_wprep<<<13,256,0,stream>>>(fc1_W, fc3_W, fc4_W, W1h, W1l, W3h, W3l, W4h, W4l);

  for (int l=0;l<NL;l++){
    float* yin  = (l&1)? y_b : y_a;
    float* yout = (l&1)? y_a : y_b;
    k_dfth<<<256,512,0,stream>>>(F1, F2);
    k_mixid<<<256,512,0,stream>>>(F2, wT + (size_t)l*589824, S1);
    if (l < NL-1){
      k_combine2<0><<<1024,512,0,stream>>>(yin, S1, x,
                                     wW + (size_t)l*1024, wb + (size_t)l*32,
                                     bW + (size_t)l*64,  bb + (size_t)l*32,
                                     cW + (size_t)l*96,  cb + (size_t)l*32,
                                     yout, F1, nullptr, nullptr);
    } else {
      k_combine2<1><<<1024,512,0,stream>>>(yin, S1, x,
                                     wW + (size_t)l*1024, wb + (size_t)l*32,
                                     bW + (size_t)l*64,  bb + (size_t)l*32,
                                     cW + (size_t)l*96,  cb + (size_t)l*32,
                                     nullptr, nullptr, Yhh, Yll_);
    }
  }

  k_headm<<<2048,256,0,stream>>>(Yhh, Yll_, W1h, W1l, fc1_b, W3h, W3l, fc3_b,
                                 W4h, W4l, fc4_b, fc5_W, fc5_b, out);
}